// Round 7
// baseline (34973.959 us; speedup 1.0000x reference)
//
#include <hip/hip_runtime.h>

typedef unsigned short u16;
typedef __attribute__((ext_vector_type(8))) short bf16x8;
typedef __attribute__((ext_vector_type(4))) float f32x4;

#define MFMA(a,b,c) __builtin_amdgcn_mfma_f32_16x16x32_bf16(a,b,c,0,0,0)

#define B_   128
#define T_   200
#define F_   171
#define FX_  256          // padded frame (8 K-chunks of 32; zero-padded weights)
#define H_   1024
#define G_   4096
#define TF_  (T_*F_)
#define BH_  (B_*H_)
#define NB_  256
#define NT_  512

__device__ __forceinline__ u16 f2bf(float v){
  union { float f; unsigned u; } c; c.f = v;
  unsigned r = (c.u + 0x7fffu + ((c.u >> 16) & 1u)) >> 16;   // RNE
  return (u16)r;
}
__device__ __forceinline__ float bf2f(u16 h){
  union { unsigned u; float f; } c; c.u = ((unsigned)h) << 16; return c.f;
}
__device__ __forceinline__ bf16x8 ld8(const u16* p){
  return *reinterpret_cast<const bf16x8*>(p);
}
__device__ __forceinline__ float sigm(float v){ return 1.f / (1.f + __expf(-v)); }

// ---------- device barrier: release-wb, hierarchical (16 leaves x 16), acquire-inv ----------
__device__ __forceinline__ void gbar(unsigned* bar, unsigned ep, int tid, int bid){
  __syncthreads();
  if (tid == 0){
    __builtin_amdgcn_fence(__ATOMIC_RELEASE, "agent");       // wb dirty L2 -> MALL
    unsigned* leaf = bar + (bid >> 4) * 16;
    unsigned* root = bar + 16 * 16;
    const unsigned old = atomicAdd(leaf, 1u);
    if (old == ep * 16u - 1u) atomicAdd(root, 1u);
    while (__hip_atomic_load(root, __ATOMIC_RELAXED, __HIP_MEMORY_SCOPE_AGENT) < ep * 16u)
      __builtin_amdgcn_s_sleep(1);
    __builtin_amdgcn_fence(__ATOMIC_ACQUIRE, "agent");       // inv stale L1/L2
  }
  __syncthreads();
}

// ---------- one LSTM layer window: 64 gate-cols x 128 batches, K split 8 waves ----------
// Resident half (wr, 64 VGPR) + streamed half (wsB). 2 rounds x 64 batches.
// KCS: streamed kc count (4 for HxH half, 1 for W1X). SS: streamed-A row stride.
// WKS: streamed-W K stride.
template<int KCS, int SS, int WKS>
__device__ __forceinline__ void layer_win(
    const bf16x8 (&wr)[4][4], const u16* __restrict__ wsB,
    const u16* __restrict__ ahr, const u16* __restrict__ alr,
    const u16* __restrict__ ahs, const u16* __restrict__ als,
    const float (&bias)[4], float (&cs)[4],
    u16* __restrict__ ohh, u16* __restrict__ ohl,
    int ug, int w, int lane, int tid, float (*red)[64][68])
{
  const int r16 = lane & 15, ke = lane >> 4, u = tid & 15;
#pragma unroll
  for (int r = 0; r < 2; ++r){
    f32x4 acc[4][4];
#pragma unroll
    for (int a = 0; a < 4; ++a)
#pragma unroll
      for (int b = 0; b < 4; ++b) acc[a][b] = (f32x4){0,0,0,0};
    // resident K-half (stride H_)
#pragma unroll
    for (int kc = 0; kc < 4; ++kc){
#pragma unroll
      for (int bt = 0; bt < 4; ++bt){
        const int ao = (r*64 + bt*16 + r16)*H_ + kc*32;
        const bf16x8 pa = ld8(ahr + ao);
        const bf16x8 pl = ld8(alr + ao);
#pragma unroll
        for (int ctt = 0; ctt < 4; ++ctt){
          acc[bt][ctt] = MFMA(pa, wr[ctt][kc], acc[bt][ctt]);
          acc[bt][ctt] = MFMA(pl, wr[ctt][kc], acc[bt][ctt]);
        }
      }
    }
    // streamed K-half
#pragma unroll
    for (int kc = 0; kc < KCS; ++kc){
      bf16x8 ws[4];
#pragma unroll
      for (int ctt = 0; ctt < 4; ++ctt) ws[ctt] = ld8(wsB + (size_t)ctt*16*WKS + kc*32);
#pragma unroll
      for (int bt = 0; bt < 4; ++bt){
        const int ao = (r*64 + bt*16 + r16)*SS + kc*32;
        const bf16x8 pa = ld8(ahs + ao);
        const bf16x8 pl = ld8(als + ao);
#pragma unroll
        for (int ctt = 0; ctt < 4; ++ctt){
          acc[bt][ctt] = MFMA(pa, ws[ctt], acc[bt][ctt]);
          acc[bt][ctt] = MFMA(pl, ws[ctt], acc[bt][ctt]);
        }
      }
    }
    // cross-wave K-reduce + cell (2 cells/thread/round)
#pragma unroll
    for (int bt = 0; bt < 4; ++bt)
#pragma unroll
      for (int ctt = 0; ctt < 4; ++ctt)
#pragma unroll
        for (int e = 0; e < 4; ++e)
          red[w][bt*16 + ke*4 + e][ctt*16 + r16] = acc[bt][ctt][e];
    __syncthreads();
#pragma unroll
    for (int j = 0; j < 2; ++j){
      const int bl = (tid >> 4)*2 + j;
      float g[4];
#pragma unroll
      for (int q = 0; q < 4; ++q){
        float s = bias[q];
#pragma unroll
        for (int ww = 0; ww < 8; ++ww) s += red[ww][bl][q*16 + u];
        g[q] = s;
      }
      const int ci = r*2 + j;
      const float cn = sigm(g[1])*cs[ci] + sigm(g[0])*tanhf(g[2]);
      const float hn = sigm(g[3])*tanhf(cn);
      cs[ci] = cn;
      const int idx = (r*64 + bl)*H_ + ug*16 + u;
      const u16 hh = f2bf(hn);
      ohh[idx] = hh;
      ohl[idx] = f2bf(hn - bf2f(hh));
    }
    __syncthreads();
  }
}

// ---------- decoder window: 16 out-cols x 128 batches, K=1024 split 8 waves ----------
__device__ __forceinline__ void dec_win(
    const u16* __restrict__ wdB,
    const u16* __restrict__ ah, const u16* __restrict__ al,
    float bd, int dct, int t,
    const float* __restrict__ x, float* __restrict__ out,
    u16* __restrict__ if_hi, u16* __restrict__ if_lo,
    int w, int lane, int tid, float (*red)[64][68])
{
  const int r16 = lane & 15, ke = lane >> 4, u = tid & 15;
  bf16x8 wd[4];
#pragma unroll
  for (int kc = 0; kc < 4; ++kc) wd[kc] = ld8(wdB + kc*32);
#pragma unroll
  for (int r = 0; r < 2; ++r){
    f32x4 acc[4];
#pragma unroll
    for (int bt = 0; bt < 4; ++bt) acc[bt] = (f32x4){0,0,0,0};
#pragma unroll
    for (int kc = 0; kc < 4; ++kc){
#pragma unroll
      for (int bt = 0; bt < 4; ++bt){
        const int ao = (r*64 + bt*16 + r16)*H_ + kc*32;
        acc[bt] = MFMA(ld8(ah + ao), wd[kc], acc[bt]);
        acc[bt] = MFMA(ld8(al + ao), wd[kc], acc[bt]);
      }
    }
#pragma unroll
    for (int bt = 0; bt < 4; ++bt)
#pragma unroll
      for (int e = 0; e < 4; ++e)
        red[w][bt*16 + ke*4 + e][r16] = acc[bt][e];
    __syncthreads();
#pragma unroll
    for (int j = 0; j < 2; ++j){
      const int bl = (tid >> 4)*2 + j;
      float v = bd;
#pragma unroll
      for (int ww = 0; ww < 8; ++ww) v += red[ww][bl][u];
      const int f = dct*16 + u, b = r*64 + bl;
      if (f < F_){
        out[(size_t)b*TF_ + (size_t)t*F_ + f] = v;
        if (t + 1 < T_){
          const bool gt = (((t+1) % 10) < 5);
          const float in = gt ? x[(size_t)b*TF_ + (size_t)(t+1)*F_ + f] : v;
          const u16 hh = f2bf(in);
          if_hi[b*FX_ + f] = hh;
          if_lo[b*FX_ + f] = f2bf(in - bf2f(hh));
        }
      }
    }
    __syncthreads();
  }
}

// ---------- main persistent kernel: 256 blocks x 512 thr, role by bid ----------
__global__ __attribute__((amdgpu_flat_work_group_size(NT_, NT_)))
           __attribute__((amdgpu_waves_per_eu(2, 2)))
void k_main(
    const float* __restrict__ x, float* __restrict__ out,
    const u16* __restrict__ W1X, const u16* __restrict__ W1H,
    const u16* __restrict__ W2,  const u16* __restrict__ W3,
    const u16* __restrict__ WD,
    const float* __restrict__ bperm, const float* __restrict__ bdec,
    u16* __restrict__ h_hi, u16* __restrict__ h_lo,
    u16* __restrict__ if_hi, u16* __restrict__ if_lo,
    unsigned* __restrict__ bar)
{
  const int tid = threadIdx.x, bid = blockIdx.x;
  const int w = tid >> 6, lane = tid & 63, r16 = lane & 15, ke = lane >> 4;
  const int u = tid & 15;
  __shared__ float red[8][64][68];                   // 139 KB K-reduce buffer

  const int role = (bid < 64) ? 0 : (bid < 128) ? 1 : (bid < 192) ? 2 : (bid < 203) ? 3 : 4;
  const int ug = bid & 63;                           // roles 0-2
  const int dct = bid - 192;                         // role 3

  bf16x8 wr[4][4];                                   // resident K-half (64 VGPR)
  float bias[4] = {0,0,0,0}, cs[4] = {0,0,0,0};
  float bd = 0.f;
  if (role <= 2){
    const size_t wks = (role == 0) ? 1024 : 2048;
    const u16* wb = ((role == 0) ? W1H : (role == 1) ? W2 : W3)
                    + (size_t)(ug*64 + r16)*wks + w*128 + ke*8;
#pragma unroll
    for (int ctt = 0; ctt < 4; ++ctt)
#pragma unroll
      for (int kc = 0; kc < 4; ++kc)
        wr[ctt][kc] = ld8(wb + (size_t)ctt*16*wks + kc*32);
    const float* bb = bperm + role*G_ + ug*64;
#pragma unroll
    for (int q = 0; q < 4; ++q) bias[q] = bb[q*16 + u];
  } else if (role == 3){
    bd = bdec[dct*16 + u];
  }

  unsigned ep = 0;
  for (int t = 0; t < T_; ++t){
    const int cur = t & 1, prv = cur ^ 1;

    // ---- slot 0: L1 (W1H resident on h0_prv; W1X streamed on if) -> h0_cur ----
    if (role == 0){
      layer_win<1, FX_, FX_>(wr,
          W1X + (size_t)(ug*64 + r16)*FX_ + w*32 + ke*8,
          h_hi + (0*2+prv)*BH_ + w*128 + ke*8, h_lo + (0*2+prv)*BH_ + w*128 + ke*8,
          if_hi + w*32 + ke*8,                 if_lo + w*32 + ke*8,
          bias, cs, h_hi + (0*2+cur)*BH_, h_lo + (0*2+cur)*BH_,
          ug, w, lane, tid, red);
    }
    ++ep; gbar(bar, ep, tid, bid);

    // ---- slot 1: L2 (h0-half resident; h1_prv-half streamed) -> h1_cur ----
    if (role == 1){
      layer_win<4, H_, 2048>(wr,
          W2 + (size_t)(ug*64 + r16)*2048 + 1024 + w*128 + ke*8,
          h_hi + (0*2+cur)*BH_ + w*128 + ke*8, h_lo + (0*2+cur)*BH_ + w*128 + ke*8,
          h_hi + (1*2+prv)*BH_ + w*128 + ke*8, h_lo + (1*2+prv)*BH_ + w*128 + ke*8,
          bias, cs, h_hi + (1*2+cur)*BH_, h_lo + (1*2+cur)*BH_,
          ug, w, lane, tid, red);
    }
    ++ep; gbar(bar, ep, tid, bid);

    // ---- slot 2: L3 (h1-half resident; h2_prv-half streamed) -> h2_cur ----
    if (role == 2){
      layer_win<4, H_, 2048>(wr,
          W3 + (size_t)(ug*64 + r16)*2048 + 1024 + w*128 + ke*8,
          h_hi + (1*2+cur)*BH_ + w*128 + ke*8, h_lo + (1*2+cur)*BH_ + w*128 + ke*8,
          h_hi + (2*2+prv)*BH_ + w*128 + ke*8, h_lo + (2*2+prv)*BH_ + w*128 + ke*8,
          bias, cs, h_hi + (2*2+cur)*BH_, h_lo + (2*2+cur)*BH_,
          ug, w, lane, tid, red);
    }
    ++ep; gbar(bar, ep, tid, bid);

    // ---- slot 3: decoder -> out(t), if(t+1) ----
    if (role == 3){
      dec_win(WD + (size_t)(dct*16 + r16)*1024 + w*128 + ke*8,
              h_hi + (2*2+cur)*BH_ + w*128 + ke*8, h_lo + (2*2+cur)*BH_ + w*128 + ke*8,
              bd, dct, t, x, out, if_hi, if_lo, w, lane, tid, red);
    }
    ++ep; gbar(bar, ep, tid, bid);
  }
}

// ---------- prep: permuted biases, decoder bias, initial in_frame ----------
__global__ void k_prep(const float* __restrict__ x,
                       const float* bi1, const float* bh1,
                       const float* bi2, const float* bh2,
                       const float* bi3, const float* bh3,
                       const float* bd_in,
                       float* __restrict__ bperm, float* __restrict__ bdec,
                       u16* __restrict__ if_hi, u16* __restrict__ if_lo)
{
  const int i = blockIdx.x * blockDim.x + threadIdx.x;
  if (i < 3*G_){
    const int l = i >> 12, r = i & 4095;
    const int ug = r >> 6, g = (r >> 4) & 3, u = r & 15;
    const int j = (g << 10) | (ug << 4) | u;          // original gate row
    const float* bi = (l == 0) ? bi1 : (l == 1) ? bi2 : bi3;
    const float* bh = (l == 0) ? bh1 : (l == 1) ? bh2 : bh3;
    bperm[i] = bi[j] + bh[j];
  }
  const int i2 = i - 3*G_;
  if (i2 >= 0 && i2 < 192) bdec[i2] = (i2 < F_) ? bd_in[i2] : 0.f;
  const int i3 = i2 - 192;
  if (i3 >= 0 && i3 < B_*FX_){
    const int b = i3 >> 8, f = i3 & 255;
    const float v = (f < F_) ? x[(size_t)b*TF_ + f] : 0.f;   // t=0 is ground-truth
    const u16 hh = f2bf(v);
    if_hi[i3] = hh;
    if_lo[i3] = f2bf(v - bf2f(hh));
  }
}

// ---------- weight convert: fp32 -> bf16, gate-permuted ----------
__global__ void k_wcvt(const float* __restrict__ Wih1, const float* __restrict__ Whh1,
                       const float* __restrict__ Wih2, const float* __restrict__ Whh2,
                       const float* __restrict__ Wih3, const float* __restrict__ Whh3,
                       const float* __restrict__ Wd_in,
                       u16* __restrict__ W1X, u16* __restrict__ W1H,
                       u16* __restrict__ W2,  u16* __restrict__ W3,
                       u16* __restrict__ WD)
{
  const int region = blockIdx.y;
  const size_t stride = (size_t)gridDim.x * blockDim.x;
  const size_t i0 = (size_t)blockIdx.x * blockDim.x + threadIdx.x;
  if (region == 0){
    for (size_t i = i0; i < (size_t)G_*FX_; i += stride){
      const int r = (int)(i >> 8), k = (int)(i & 255);
      const int ug = r >> 6, g = (r >> 4) & 3, u = r & 15;
      const int j = (g << 10) | (ug << 4) | u;
      W1X[i] = f2bf((k < F_) ? Wih1[(size_t)j*F_ + k] : 0.f);
    }
  } else if (region == 1){
    for (size_t i = i0; i < (size_t)G_*H_; i += stride){
      const int r = (int)(i >> 10), k = (int)(i & 1023);
      const int ug = r >> 6, g = (r >> 4) & 3, u = r & 15;
      const int j = (g << 10) | (ug << 4) | u;
      W1H[i] = f2bf(Whh1[(size_t)j*H_ + k]);
    }
  } else if (region == 2){
    for (size_t i = i0; i < (size_t)G_*2048; i += stride){
      const int r = (int)(i >> 11), k = (int)(i & 2047);
      const int ug = r >> 6, g = (r >> 4) & 3, u = r & 15;
      const int j = (g << 10) | (ug << 4) | u;
      W2[i] = f2bf((k < H_) ? Wih2[(size_t)j*H_ + k] : Whh2[(size_t)j*H_ + (k - H_)]);
    }
  } else if (region == 3){
    for (size_t i = i0; i < (size_t)G_*2048; i += stride){
      const int r = (int)(i >> 11), k = (int)(i & 2047);
      const int ug = r >> 6, g = (r >> 4) & 3, u = r & 15;
      const int j = (g << 10) | (ug << 4) | u;
      W3[i] = f2bf((k < H_) ? Wih3[(size_t)j*H_ + k] : Whh3[(size_t)j*H_ + (k - H_)]);
    }
  } else {
    for (size_t i = i0; i < (size_t)176*H_; i += stride){
      const int r = (int)(i >> 10), k = (int)(i & 1023);
      WD[i] = f2bf((r < F_) ? Wd_in[(size_t)r*H_ + k] : 0.f);
    }
  }
}

extern "C" void kernel_launch(void* const* d_in, const int* in_sizes, int n_in,
                              void* d_out, int out_size, void* d_ws, size_t ws_size,
                              hipStream_t stream)
{
  const float* x    = (const float*)d_in[0];
  const float* Wih1 = (const float*)d_in[1];
  const float* bih1 = (const float*)d_in[2];
  const float* Whh1 = (const float*)d_in[3];
  const float* bhh1 = (const float*)d_in[4];
  const float* Wih2 = (const float*)d_in[5];
  const float* bih2 = (const float*)d_in[6];
  const float* Whh2 = (const float*)d_in[7];
  const float* bhh2 = (const float*)d_in[8];
  const float* Wih3 = (const float*)d_in[9];
  const float* bih3 = (const float*)d_in[10];
  const float* Whh3 = (const float*)d_in[11];
  const float* bhh3 = (const float*)d_in[12];
  const float* Wdec = (const float*)d_in[13];
  const float* bdec_in = (const float*)d_in[14];
  float* out = (float*)d_out;

  char* ws = (char*)d_ws;
  size_t off = 0;
  auto alloc = [&](size_t bytes) -> void* {
    void* p = ws + off;
    off = (off + bytes + 255) & ~(size_t)255;
    return p;
  };
  unsigned* bar = (unsigned*)alloc(4096);        // 16 leaves + root, 64B-spaced
  u16* h_hi  = (u16*)alloc((size_t)3*2*BH_*2);
  u16* h_lo  = (u16*)alloc((size_t)3*2*BH_*2);
  u16* if_hi = (u16*)alloc((size_t)B_*FX_*2);
  u16* if_lo = (u16*)alloc((size_t)B_*FX_*2);
  const size_t zero_bytes = off;                 // state zone: re-zeroed every launch
  u16* W1X = (u16*)alloc((size_t)G_*FX_*2);
  u16* W1H = (u16*)alloc((size_t)G_*H_*2);
  u16* W2  = (u16*)alloc((size_t)G_*2048*2);
  u16* W3  = (u16*)alloc((size_t)G_*2048*2);
  u16* WD  = (u16*)alloc((size_t)176*H_*2);
  float* bperm = (float*)alloc((size_t)3*G_*4);
  float* bdec  = (float*)alloc((size_t)192*4);

  hipMemsetAsync(d_ws, 0, zero_bytes, stream);
  k_prep<<<180, 256, 0, stream>>>(x, bih1, bhh1, bih2, bhh2, bih3, bhh3, bdec_in,
                                  bperm, bdec, if_hi, if_lo);
  k_wcvt<<<dim3(2048, 5), 256, 0, stream>>>(Wih1, Whh1, Wih2, Whh2, Wih3, Whh3, Wdec,
                                            W1X, W1H, W2, W3, WD);
  k_main<<<NB_, NT_, 0, stream>>>(x, out, W1X, W1H, W2, W3, WD, bperm, bdec,
                                  h_hi, h_lo, if_hi, if_lo, bar);
}

// Round 8
// 28691.858 us; speedup vs baseline: 1.2190x; 1.2190x over previous
//
#include <hip/hip_runtime.h>

typedef unsigned short u16;
typedef __attribute__((ext_vector_type(8))) short bf16x8;
typedef __attribute__((ext_vector_type(4))) float f32x4;

#define MFMA(a,b,c) __builtin_amdgcn_mfma_f32_16x16x32_bf16(a,b,c,0,0,0)

#define B_   128
#define T_   200
#define F_   171
#define FX_  256          // padded frame (8 K-chunks of 32; zero-padded weights)
#define H_   1024
#define G_   4096
#define TF_  (T_*F_)
#define BH_  (B_*H_)
#define NB_  256
#define NT_  512

__device__ __forceinline__ u16 f2bf(float v){
  union { float f; unsigned u; } c; c.f = v;
  unsigned r = (c.u + 0x7fffu + ((c.u >> 16) & 1u)) >> 16;   // RNE
  return (u16)r;
}
__device__ __forceinline__ float bf2f(u16 h){
  union { unsigned u; float f; } c; c.u = ((unsigned)h) << 16; return c.f;
}
__device__ __forceinline__ bf16x8 ld8(const u16* p){
  return *reinterpret_cast<const bf16x8*>(p);
}
__device__ __forceinline__ float sigm(float v){ return 1.f / (1.f + __expf(-v)); }

// ---------- device barrier: release-wb, hierarchical (16 leaves x 16), acquire-inv ----------
__device__ __forceinline__ void gbar(unsigned* bar, unsigned ep, int tid, int bid){
  __syncthreads();
  if (tid == 0){
    __builtin_amdgcn_fence(__ATOMIC_RELEASE, "agent");       // wb dirty L2 -> MALL
    unsigned* leaf = bar + (bid >> 4) * 16;
    unsigned* root = bar + 16 * 16;
    const unsigned old = atomicAdd(leaf, 1u);
    if (old == ep * 16u - 1u) atomicAdd(root, 1u);
    while (__hip_atomic_load(root, __ATOMIC_RELAXED, __HIP_MEMORY_SCOPE_AGENT) < ep * 16u)
      __builtin_amdgcn_s_sleep(1);
    __builtin_amdgcn_fence(__ATOMIC_ACQUIRE, "agent");       // inv stale L1/L2
  }
  __syncthreads();
}

// ---------- GEMM on resident weights: KC K-chunks x 8 batch-tiles -> red[w] ----------
template<int KC, int RS>
__device__ __forceinline__ void gemm_red(
    const bf16x8* wreg, const u16* __restrict__ ah, const u16* __restrict__ al,
    int w, int r16, int ke, float (*red)[128][19])
{
  f32x4 acc[8];
#pragma unroll
  for (int bt = 0; bt < 8; ++bt) acc[bt] = (f32x4){0,0,0,0};
#pragma unroll
  for (int kc = 0; kc < KC; ++kc){
#pragma unroll
    for (int bt = 0; bt < 8; ++bt){
      const int ao = (bt*16 + r16)*RS + kc*32;
      acc[bt] = MFMA(ld8(ah + ao), wreg[kc], acc[bt]);
      acc[bt] = MFMA(ld8(al + ao), wreg[kc], acc[bt]);
    }
  }
#pragma unroll
  for (int bt = 0; bt < 8; ++bt)
#pragma unroll
    for (int e = 0; e < 4; ++e)
      red[w][bt*16 + ke*4 + e][r16] = acc[bt][e];
}

// ---------- cell update: thread owns (batch bl, unit u2); block owns units bid*4..+4 ----------
__device__ __forceinline__ void cell_update(
    const float* bias4, float& c, bool addgp,
    u16* __restrict__ ohh, u16* __restrict__ ohl,
    int bid, int bl, int u2, float (*red)[128][19], float (*gp)[16])
{
  float g[4];
#pragma unroll
  for (int q = 0; q < 4; ++q){
    float s = bias4[q];
#pragma unroll
    for (int ww = 0; ww < 8; ++ww) s += red[ww][bl][q*4 + u2];
    if (addgp) s += gp[bl][q*4 + u2];
    g[q] = s;
  }
  const float cn = sigm(g[1])*c + sigm(g[0])*tanhf(g[2]);
  const float hn = sigm(g[3])*tanhf(cn);
  c = cn;
  const int idx = bl*H_ + bid*4 + u2;
  const u16 hh = f2bf(hn);
  ohh[idx] = hh;
  ohl[idx] = f2bf(hn - bf2f(hh));
}

// ---------- main persistent kernel: 256 blocks x 512 thr; block = 16 gate-cols, ALL layers ----------
__global__ __attribute__((amdgpu_flat_work_group_size(NT_, NT_)))
           __attribute__((amdgpu_waves_per_eu(2, 2)))
void k_main(
    const float* __restrict__ x, float* __restrict__ out,
    const u16* __restrict__ W1X, const u16* __restrict__ W1H,
    const u16* __restrict__ W2,  const u16* __restrict__ W3,
    const u16* __restrict__ WD,
    const float* __restrict__ bperm, const float* __restrict__ bdec,
    u16* __restrict__ h_hi, u16* __restrict__ h_lo,
    u16* __restrict__ if_hi, u16* __restrict__ if_lo,
    unsigned* __restrict__ bar)
{
  const int tid = threadIdx.x, bid = blockIdx.x;
  const int w = tid >> 6, lane = tid & 63, r16 = lane & 15, ke = lane >> 4;
  const int bl = tid >> 2, u2 = tid & 3;             // cell mapping: 128 b x 4 units
  __shared__ float red[8][128][19];                  // 74 KB K-reduce
  __shared__ float gp[128][16];                      // 8 KB L1 h-part stash (86 KB tot -> 1 blk/CU)

  // ---- resident weights: block's 16 gate-cols for all three layers ----
  const size_t wrow = (size_t)(bid*16 + r16);
  bf16x8 w2r[8], w3r[8], w1h[4], w1x;
#pragma unroll
  for (int kc = 0; kc < 8; ++kc) w2r[kc] = ld8(W2 + wrow*2048 + w*256 + kc*32 + ke*8);
#pragma unroll
  for (int kc = 0; kc < 8; ++kc) w3r[kc] = ld8(W3 + wrow*2048 + w*256 + kc*32 + ke*8);
#pragma unroll
  for (int kc = 0; kc < 4; ++kc) w1h[kc] = ld8(W1H + wrow*1024 + w*128 + kc*32 + ke*8);
  w1x = ld8(W1X + wrow*FX_ + w*32 + ke*8);

  float bias[3][4], cs[3] = {0.f, 0.f, 0.f};
#pragma unroll
  for (int l = 0; l < 3; ++l)
#pragma unroll
    for (int q = 0; q < 4; ++q) bias[l][q] = bperm[l*G_ + bid*16 + q*4 + u2];

  // decoder block mapping (bid < 88): 11 col-tiles x 8 batch-tiles
  const int dct = bid >> 3, db = bid & 7;
  const float bd = (bid < 88) ? bdec[dct*16 + (tid & 15)] : 0.f;

  // zero the L1 h-part stash (t=0: h0_prev = 0)
  for (int i = tid; i < 128*16; i += NT_) gp[i >> 4][i & 15] = 0.f;
  __syncthreads();

  unsigned ep = 0;
  for (int t = 0; t < T_; ++t){
    const int cur = t & 1, prv = cur ^ 1;
    u16* h0c_h = h_hi + (0*2+cur)*BH_; u16* h0c_l = h_lo + (0*2+cur)*BH_;
    u16* h1c_h = h_hi + (1*2+cur)*BH_; u16* h1c_l = h_lo + (1*2+cur)*BH_;
    u16* h2c_h = h_hi + (2*2+cur)*BH_; u16* h2c_l = h_lo + (2*2+cur)*BH_;
    const u16* h1p_h = h_hi + (1*2+prv)*BH_; const u16* h1p_l = h_lo + (1*2+prv)*BH_;
    const u16* h2p_h = h_hi + (2*2+prv)*BH_; const u16* h2p_l = h_lo + (2*2+prv)*BH_;

    // ---- P1: gates0 = gpart(W1H*h0_prv) + W1X*if(t); cell -> h0_cur ----
    gemm_red<1, FX_>(&w1x, if_hi + w*32 + ke*8, if_lo + w*32 + ke*8, w, r16, ke, red);
    __syncthreads();
    cell_update(bias[0], cs[0], true, h0c_h, h0c_l, bid, bl, u2, red, gp);
    ++ep; gbar(bar, ep, tid, bid);

    // ---- P2: gates1 = W2 * [h0_cur | h1_prv]; cell -> h1_cur ----
    {
      const u16* ah = (w < 4 ? h0c_h : h1p_h) + (w & 3)*256 + ke*8;
      const u16* al = (w < 4 ? h0c_l : h1p_l) + (w & 3)*256 + ke*8;
      gemm_red<8, H_>(w2r, ah, al, w, r16, ke, red);
    }
    __syncthreads();
    cell_update(bias[1], cs[1], false, h1c_h, h1c_l, bid, bl, u2, red, gp);
    ++ep; gbar(bar, ep, tid, bid);

    // ---- P3: gates2 = W3 * [h1_cur | h2_prv]; cell -> h2_cur ----
    {
      const u16* ah = (w < 4 ? h1c_h : h2p_h) + (w & 3)*256 + ke*8;
      const u16* al = (w < 4 ? h1c_l : h2p_l) + (w & 3)*256 + ke*8;
      gemm_red<8, H_>(w3r, ah, al, w, r16, ke, red);
    }
    __syncthreads();
    cell_update(bias[2], cs[2], false, h2c_h, h2c_l, bid, bl, u2, red, gp);
    ++ep; gbar(bar, ep, tid, bid);

    // ---- P4: gpart = W1H * h0_cur (all blocks); decoder -> out(t), if(t+1) (88 blocks) ----
    gemm_red<4, H_>(w1h, h0c_h + w*128 + ke*8, h0c_l + w*128 + ke*8, w, r16, ke, red);
    __syncthreads();
#pragma unroll
    for (int q = 0; q < 4; ++q){
      float s = 0.f;
#pragma unroll
      for (int ww = 0; ww < 8; ++ww) s += red[ww][bl][q*4 + u2];
      gp[bl][q*4 + u2] = s;
    }
    if (bid < 88){
      __syncthreads();                               // red reused by decoder
      f32x4 dacc = {0,0,0,0};
#pragma unroll
      for (int kc = 0; kc < 4; ++kc){
        const bf16x8 wd = ld8(WD + (size_t)(dct*16 + r16)*1024 + w*128 + kc*32 + ke*8);
        const int ao = (db*16 + r16)*H_ + w*128 + kc*32 + ke*8;
        dacc = MFMA(ld8(h2c_h + ao), wd, dacc);
        dacc = MFMA(ld8(h2c_l + ao), wd, dacc);
      }
#pragma unroll
      for (int e = 0; e < 4; ++e) red[w][ke*4 + e][r16] = dacc[e];
      __syncthreads();
      if (tid < 256){
        const int bl2 = tid >> 4, fl = tid & 15;
        float v = bd;
#pragma unroll
        for (int ww = 0; ww < 8; ++ww) v += red[ww][bl2][fl];
        const int f = dct*16 + fl, b = db*16 + bl2;
        if (f < F_){
          out[(size_t)b*TF_ + (size_t)t*F_ + f] = v;
          if (t + 1 < T_){
            const bool gt = (((t+1) % 10) < 5);
            const float in = gt ? x[(size_t)b*TF_ + (size_t)(t+1)*F_ + f] : v;
            const u16 hh = f2bf(in);
            if_hi[b*FX_ + f] = hh;
            if_lo[b*FX_ + f] = f2bf(in - bf2f(hh));
          }
        }
      }
    }
    ++ep; gbar(bar, ep, tid, bid);
  }
}

// ---------- prep: permuted biases, decoder bias, initial in_frame ----------
// permutation: permuted row i = blk*16 + g*4 + u2  <->  original j = (g<<10)|(blk<<2)|u2
__global__ void k_prep(const float* __restrict__ x,
                       const float* bi1, const float* bh1,
                       const float* bi2, const float* bh2,
                       const float* bi3, const float* bh3,
                       const float* bd_in,
                       float* __restrict__ bperm, float* __restrict__ bdec,
                       u16* __restrict__ if_hi, u16* __restrict__ if_lo)
{
  const int i = blockIdx.x * blockDim.x + threadIdx.x;
  if (i < 3*G_){
    const int l = i >> 12, r = i & 4095;
    const int blk = r >> 4, g = (r >> 2) & 3, u2 = r & 3;
    const int j = (g << 10) | (blk << 2) | u2;
    const float* bi = (l == 0) ? bi1 : (l == 1) ? bi2 : bi3;
    const float* bh = (l == 0) ? bh1 : (l == 1) ? bh2 : bh3;
    bperm[i] = bi[j] + bh[j];
  }
  const int i2 = i - 3*G_;
  if (i2 >= 0 && i2 < 192) bdec[i2] = (i2 < F_) ? bd_in[i2] : 0.f;
  const int i3 = i2 - 192;
  if (i3 >= 0 && i3 < B_*FX_){
    const int b = i3 >> 8, f = i3 & 255;
    const float v = (f < F_) ? x[(size_t)b*TF_ + f] : 0.f;   // t=0 is ground-truth
    const u16 hh = f2bf(v);
    if_hi[i3] = hh;
    if_lo[i3] = f2bf(v - bf2f(hh));
  }
}

// ---------- weight convert: fp32 -> bf16, permuted (blk*16 + g*4 + u2) ----------
__global__ void k_wcvt(const float* __restrict__ Wih1, const float* __restrict__ Whh1,
                       const float* __restrict__ Wih2, const float* __restrict__ Whh2,
                       const float* __restrict__ Wih3, const float* __restrict__ Whh3,
                       const float* __restrict__ Wd_in,
                       u16* __restrict__ W1X, u16* __restrict__ W1H,
                       u16* __restrict__ W2,  u16* __restrict__ W3,
                       u16* __restrict__ WD)
{
  const int region = blockIdx.y;
  const size_t stride = (size_t)gridDim.x * blockDim.x;
  const size_t i0 = (size_t)blockIdx.x * blockDim.x + threadIdx.x;
  if (region == 0){
    for (size_t i = i0; i < (size_t)G_*FX_; i += stride){
      const int r = (int)(i >> 8), k = (int)(i & 255);
      const int blk = r >> 4, g = (r >> 2) & 3, u2 = r & 3;
      const int j = (g << 10) | (blk << 2) | u2;
      W1X[i] = f2bf((k < F_) ? Wih1[(size_t)j*F_ + k] : 0.f);
    }
  } else if (region == 1){
    for (size_t i = i0; i < (size_t)G_*H_; i += stride){
      const int r = (int)(i >> 10), k = (int)(i & 1023);
      const int blk = r >> 4, g = (r >> 2) & 3, u2 = r & 3;
      const int j = (g << 10) | (blk << 2) | u2;
      W1H[i] = f2bf(Whh1[(size_t)j*H_ + k]);
    }
  } else if (region == 2){
    for (size_t i = i0; i < (size_t)G_*2048; i += stride){
      const int r = (int)(i >> 11), k = (int)(i & 2047);
      const int blk = r >> 4, g = (r >> 2) & 3, u2 = r & 3;
      const int j = (g << 10) | (blk << 2) | u2;
      W2[i] = f2bf((k < H_) ? Wih2[(size_t)j*H_ + k] : Whh2[(size_t)j*H_ + (k - H_)]);
    }
  } else if (region == 3){
    for (size_t i = i0; i < (size_t)G_*2048; i += stride){
      const int r = (int)(i >> 11), k = (int)(i & 2047);
      const int blk = r >> 4, g = (r >> 2) & 3, u2 = r & 3;
      const int j = (g << 10) | (blk << 2) | u2;
      W3[i] = f2bf((k < H_) ? Wih3[(size_t)j*H_ + k] : Whh3[(size_t)j*H_ + (k - H_)]);
    }
  } else {
    for (size_t i = i0; i < (size_t)176*H_; i += stride){
      const int r = (int)(i >> 10), k = (int)(i & 1023);
      WD[i] = f2bf((r < F_) ? Wd_in[(size_t)r*H_ + k] : 0.f);
    }
  }
}

extern "C" void kernel_launch(void* const* d_in, const int* in_sizes, int n_in,
                              void* d_out, int out_size, void* d_ws, size_t ws_size,
                              hipStream_t stream)
{
  const float* x    = (const float*)d_in[0];
  const float* Wih1 = (const float*)d_in[1];
  const float* bih1 = (const float*)d_in[2];
  const float* Whh1 = (const float*)d_in[3];
  const float* bhh1 = (const float*)d_in[4];
  const float* Wih2 = (const float*)d_in[5];
  const float* bih2 = (const float*)d_in[6];
  const float* Whh2 = (const float*)d_in[7];
  const float* bhh2 = (const float*)d_in[8];
  const float* Wih3 = (const float*)d_in[9];
  const float* bih3 = (const float*)d_in[10];
  const float* Whh3 = (const float*)d_in[11];
  const float* bhh3 = (const float*)d_in[12];
  const float* Wdec = (const float*)d_in[13];
  const float* bdec_in = (const float*)d_in[14];
  float* out = (float*)d_out;

  char* ws = (char*)d_ws;
  size_t off = 0;
  auto alloc = [&](size_t bytes) -> void* {
    void* p = ws + off;
    off = (off + bytes + 255) & ~(size_t)255;
    return p;
  };
  unsigned* bar = (unsigned*)alloc(4096);        // 16 leaves + root, 64B-spaced
  u16* h_hi  = (u16*)alloc((size_t)3*2*BH_*2);
  u16* h_lo  = (u16*)alloc((size_t)3*2*BH_*2);
  u16* if_hi = (u16*)alloc((size_t)B_*FX_*2);
  u16* if_lo = (u16*)alloc((size_t)B_*FX_*2);
  const size_t zero_bytes = off;                 // state zone: re-zeroed every launch
  u16* W1X = (u16*)alloc((size_t)G_*FX_*2);
  u16* W1H = (u16*)alloc((size_t)G_*H_*2);
  u16* W2  = (u16*)alloc((size_t)G_*2048*2);
  u16* W3  = (u16*)alloc((size_t)G_*2048*2);
  u16* WD  = (u16*)alloc((size_t)176*H_*2);
  float* bperm = (float*)alloc((size_t)3*G_*4);
  float* bdec  = (float*)alloc((size_t)192*4);

  hipMemsetAsync(d_ws, 0, zero_bytes, stream);
  k_prep<<<180, 256, 0, stream>>>(x, bih1, bhh1, bih2, bhh2, bih3, bhh3, bdec_in,
                                  bperm, bdec, if_hi, if_lo);
  k_wcvt<<<dim3(2048, 5), 256, 0, stream>>>(Wih1, Whh1, Wih2, Whh2, Wih3, Whh3, Wdec,
                                            W1X, W1H, W2, W3, WD);
  k_main<<<NB_, NT_, 0, stream>>>(x, out, W1X, W1H, W2, W3, WD, bperm, bdec,
                                  h_hi, h_lo, if_hi, if_lo, bar);
}

// Round 9
// 22159.598 us; speedup vs baseline: 1.5783x; 1.2948x over previous
//
#include <hip/hip_runtime.h>

typedef unsigned short u16;
typedef __attribute__((ext_vector_type(8))) short bf16x8;
typedef __attribute__((ext_vector_type(4))) float f32x4;

#define MFMA(a,b,c) __builtin_amdgcn_mfma_f32_16x16x32_bf16(a,b,c,0,0,0)

#define B_   128
#define T_   200
#define F_   171
#define FX_  256          // padded frame (8 K-chunks of 32; zero-padded weights)
#define H_   1024
#define G_   4096
#define TF_  (T_*F_)
#define BH_  (B_*H_)
#define NB_  256
#define NT_  512

__device__ __forceinline__ u16 f2bf(float v){
  union { float f; unsigned u; } c; c.f = v;
  unsigned r = (c.u + 0x7fffu + ((c.u >> 16) & 1u)) >> 16;   // RNE
  return (u16)r;
}
__device__ __forceinline__ float bf2f(u16 h){
  union { unsigned u; float f; } c; c.u = ((unsigned)h) << 16; return c.f;
}
__device__ __forceinline__ bf16x8 ld8(const u16* p){
  return *reinterpret_cast<const bf16x8*>(p);
}
// agent-scope write-through store (h/if): visible at MALL without any release fence
__device__ __forceinline__ void st2a(u16* p, u16 v){
  __hip_atomic_store(p, v, __ATOMIC_RELAXED, __HIP_MEMORY_SCOPE_AGENT);
}
__device__ __forceinline__ float sigm(float v){ return 1.f / (1.f + __expf(-v)); }

// ---------- device barrier: leaf-per-XCD arrive, ONE L2-inv per XCD by leader ----------
// h/if stores are write-through (st2a), so no release fence is needed anywhere.
// bar dword layout: [0..255] leaf[xcd]*16 | [256] root | [272..527] flag[xcd]*16
//                   [528..543] census buckets | [560] census root
__device__ __forceinline__ void gbar(unsigned* bar, unsigned ep, int tid,
                                     bool leader, unsigned xcd,
                                     unsigned n_my, unsigned x_act){
  __syncthreads();                                   // drains vmcnt: stores at MALL
  if (tid == 0){
    unsigned* leaf = bar + xcd*16;
    unsigned* root = bar + 256;
    unsigned* flag = bar + 272 + xcd*16;
    const unsigned r = __hip_atomic_fetch_add(leaf, 1u, __ATOMIC_RELAXED, __HIP_MEMORY_SCOPE_AGENT);
    if (r == ep * n_my - 1u)                         // last arriver on this XCD
      __hip_atomic_fetch_add(root, 1u, __ATOMIC_RELAXED, __HIP_MEMORY_SCOPE_AGENT);
    if (leader){
      while (__hip_atomic_load(root, __ATOMIC_RELAXED, __HIP_MEMORY_SCOPE_AGENT) < ep * x_act)
        __builtin_amdgcn_s_sleep(1);
      __builtin_amdgcn_fence(__ATOMIC_ACQUIRE, "agent");   // single buffer_inv for this XCD
      __hip_atomic_store(flag, ep, __ATOMIC_RELEASE, __HIP_MEMORY_SCOPE_AGENT);
    } else {
      while (__hip_atomic_load(flag, __ATOMIC_RELAXED, __HIP_MEMORY_SCOPE_AGENT) < ep)
        __builtin_amdgcn_s_sleep(1);
    }
  }
  asm volatile("" ::: "memory");
  __syncthreads();
}

// ---------- GEMM on resident weights: KC K-chunks x 8 batch-tiles -> red[w] ----------
template<int KC, int RS>
__device__ __forceinline__ void gemm_red(
    const bf16x8* wreg, const u16* __restrict__ ah, const u16* __restrict__ al,
    int w, int r16, int ke, float (*red)[128][20])
{
  f32x4 acc[8];
#pragma unroll
  for (int bt = 0; bt < 8; ++bt) acc[bt] = (f32x4){0,0,0,0};
#pragma unroll
  for (int kc = 0; kc < KC; ++kc){
#pragma unroll
    for (int bt = 0; bt < 8; ++bt){
      const int ao = (bt*16 + r16)*RS + kc*32;
      acc[bt] = MFMA(ld8(ah + ao), wreg[kc], acc[bt]);
      acc[bt] = MFMA(ld8(al + ao), wreg[kc], acc[bt]);
    }
  }
#pragma unroll
  for (int bt = 0; bt < 8; ++bt)
#pragma unroll
    for (int e = 0; e < 4; ++e)
      red[w][bt*16 + ke*4 + e][r16] = acc[bt][e];
}

// ---------- cell update: thread owns (batch bl, unit u2); block owns units bid*4..+4 ----------
__device__ __forceinline__ void cell_update(
    const float* bias4, float& c, bool addgp,
    u16* __restrict__ ohh, u16* __restrict__ ohl,
    int bid, int bl, int u2, float (*red)[128][20], float (*gp)[16])
{
  float g[4];
#pragma unroll
  for (int q = 0; q < 4; ++q){
    float s = bias4[q];
#pragma unroll
    for (int ww = 0; ww < 8; ++ww) s += red[ww][bl][q*4 + u2];
    if (addgp) s += gp[bl][q*4 + u2];
    g[q] = s;
  }
  const float cn = sigm(g[1])*c + sigm(g[0])*tanhf(g[2]);
  const float hn = sigm(g[3])*tanhf(cn);
  c = cn;
  const int idx = bl*H_ + bid*4 + u2;
  const u16 hh = f2bf(hn);
  st2a(ohh + idx, hh);
  st2a(ohl + idx, f2bf(hn - bf2f(hh)));
}

// ---------- main persistent kernel: 256 blocks x 512 thr; block = 16 gate-cols, ALL layers ----------
__global__ __attribute__((amdgpu_flat_work_group_size(NT_, NT_)))
           __attribute__((amdgpu_waves_per_eu(2, 2)))
void k_main(
    const float* __restrict__ x, float* __restrict__ out,
    const u16* __restrict__ W1X, const u16* __restrict__ W1H,
    const u16* __restrict__ W2,  const u16* __restrict__ W3,
    const u16* __restrict__ WD,
    const float* __restrict__ bperm, const float* __restrict__ bdec,
    u16* __restrict__ h_hi, u16* __restrict__ h_lo,
    u16* __restrict__ if_hi, u16* __restrict__ if_lo,
    unsigned* __restrict__ bar)
{
  const int tid = threadIdx.x, bid = blockIdx.x;
  const int w = tid >> 6, lane = tid & 63, r16 = lane & 15, ke = lane >> 4;
  const int bl = tid >> 2, u2 = tid & 3;             // cell mapping: 128 b x 4 units
  __shared__ float red[8][128][20];                  // 80 KB K-reduce (padded rows)
  __shared__ float gp[128][16];                      // 8 KB L1 h-part stash
  __shared__ unsigned s_info[3];

  // ---- one-time census: per-XCD rank, block count, active-XCD count ----
  unsigned xcc; asm volatile("s_getreg_b32 %0, hwreg(HW_REG_XCC_ID)" : "=s"(xcc));
  xcc &= 15;
  if (tid == 0){
    unsigned* chk   = bar + 528;
    unsigned* iroot = bar + 560;
    const unsigned rank = __hip_atomic_fetch_add(&chk[xcc], 1u, __ATOMIC_RELAXED, __HIP_MEMORY_SCOPE_AGENT);
    __builtin_amdgcn_fence(__ATOMIC_RELEASE, "agent");
    __hip_atomic_fetch_add(iroot, 1u, __ATOMIC_RELAXED, __HIP_MEMORY_SCOPE_AGENT);
    while (__hip_atomic_load(iroot, __ATOMIC_RELAXED, __HIP_MEMORY_SCOPE_AGENT) < (unsigned)NB_)
      __builtin_amdgcn_s_sleep(1);
    __builtin_amdgcn_fence(__ATOMIC_ACQUIRE, "agent");
    unsigned xact = 0;
    for (int i = 0; i < 16; ++i)
      xact += (__hip_atomic_load(&chk[i], __ATOMIC_RELAXED, __HIP_MEMORY_SCOPE_AGENT) != 0u);
    s_info[0] = rank;
    s_info[1] = __hip_atomic_load(&chk[xcc], __ATOMIC_RELAXED, __HIP_MEMORY_SCOPE_AGENT);
    s_info[2] = xact;
  }
  __syncthreads();
  const bool leader = (s_info[0] == 0u);
  const unsigned n_my = s_info[1], x_act = s_info[2];

  // ---- resident weights: block's 16 gate-cols for all three layers ----
  const size_t wrow = (size_t)(bid*16 + r16);
  bf16x8 w2r[8], w3r[8], w1h[4], w1x;
#pragma unroll
  for (int kc = 0; kc < 8; ++kc) w2r[kc] = ld8(W2 + wrow*2048 + w*256 + kc*32 + ke*8);
#pragma unroll
  for (int kc = 0; kc < 8; ++kc) w3r[kc] = ld8(W3 + wrow*2048 + w*256 + kc*32 + ke*8);
#pragma unroll
  for (int kc = 0; kc < 4; ++kc) w1h[kc] = ld8(W1H + wrow*1024 + w*128 + kc*32 + ke*8);
  w1x = ld8(W1X + wrow*FX_ + w*32 + ke*8);

  float bias[3][4], cs[3] = {0.f, 0.f, 0.f};
#pragma unroll
  for (int l = 0; l < 3; ++l)
#pragma unroll
    for (int q = 0; q < 4; ++q) bias[l][q] = bperm[l*G_ + bid*16 + q*4 + u2];

  // decoder block mapping (bid < 88): 11 col-tiles x 8 batch-tiles
  const int dct = bid >> 3, db = bid & 7;
  const float bd = (bid < 88) ? bdec[dct*16 + (tid & 15)] : 0.f;

  // zero the L1 h-part stash (t=0: h0_prev = 0)
  for (int i = tid; i < 128*16; i += NT_) gp[i >> 4][i & 15] = 0.f;
  __syncthreads();

  unsigned ep = 0;
  for (int t = 0; t < T_; ++t){
    const int cur = t & 1, prv = cur ^ 1;
    u16* h0c_h = h_hi + (0*2+cur)*BH_; u16* h0c_l = h_lo + (0*2+cur)*BH_;
    u16* h1c_h = h_hi + (1*2+cur)*BH_; u16* h1c_l = h_lo + (1*2+cur)*BH_;
    u16* h2c_h = h_hi + (2*2+cur)*BH_; u16* h2c_l = h_lo + (2*2+cur)*BH_;
    const u16* h1p_h = h_hi + (1*2+prv)*BH_; const u16* h1p_l = h_lo + (1*2+prv)*BH_;
    const u16* h2p_h = h_hi + (2*2+prv)*BH_; const u16* h2p_l = h_lo + (2*2+prv)*BH_;

    // ---- P1: gates0 = gpart(W1H*h0_prv) + W1X*if(t); cell -> h0_cur ----
    gemm_red<1, FX_>(&w1x, if_hi + w*32 + ke*8, if_lo + w*32 + ke*8, w, r16, ke, red);
    __syncthreads();
    cell_update(bias[0], cs[0], true, h0c_h, h0c_l, bid, bl, u2, red, gp);
    ++ep; gbar(bar, ep, tid, leader, xcc, n_my, x_act);

    // ---- P2: gates1 = W2 * [h0_cur | h1_prv]; cell -> h1_cur ----
    {
      const u16* ah = (w < 4 ? h0c_h : h1p_h) + (w & 3)*256 + ke*8;
      const u16* al = (w < 4 ? h0c_l : h1p_l) + (w & 3)*256 + ke*8;
      gemm_red<8, H_>(w2r, ah, al, w, r16, ke, red);
    }
    __syncthreads();
    cell_update(bias[1], cs[1], false, h1c_h, h1c_l, bid, bl, u2, red, gp);
    ++ep; gbar(bar, ep, tid, leader, xcc, n_my, x_act);

    // ---- P3: gates2 = W3 * [h1_cur | h2_prv]; cell -> h2_cur ----
    {
      const u16* ah = (w < 4 ? h1c_h : h2p_h) + (w & 3)*256 + ke*8;
      const u16* al = (w < 4 ? h1c_l : h2p_l) + (w & 3)*256 + ke*8;
      gemm_red<8, H_>(w3r, ah, al, w, r16, ke, red);
    }
    __syncthreads();
    cell_update(bias[2], cs[2], false, h2c_h, h2c_l, bid, bl, u2, red, gp);
    ++ep; gbar(bar, ep, tid, leader, xcc, n_my, x_act);

    // ---- P4: gpart = W1H * h0_cur (all blocks); decoder -> out(t), if(t+1) (88 blocks) ----
    gemm_red<4, H_>(w1h, h0c_h + w*128 + ke*8, h0c_l + w*128 + ke*8, w, r16, ke, red);
    __syncthreads();
#pragma unroll
    for (int q = 0; q < 4; ++q){
      float s = 0.f;
#pragma unroll
      for (int ww = 0; ww < 8; ++ww) s += red[ww][bl][q*4 + u2];
      gp[bl][q*4 + u2] = s;
    }
    if (bid < 88){
      __syncthreads();                               // red reused by decoder
      f32x4 dacc = {0,0,0,0};
#pragma unroll
      for (int kc = 0; kc < 4; ++kc){
        const bf16x8 wd = ld8(WD + (size_t)(dct*16 + r16)*1024 + w*128 + kc*32 + ke*8);
        const int ao = (db*16 + r16)*H_ + w*128 + kc*32 + ke*8;
        dacc = MFMA(ld8(h2c_h + ao), wd, dacc);
        dacc = MFMA(ld8(h2c_l + ao), wd, dacc);
      }
#pragma unroll
      for (int e = 0; e < 4; ++e) red[w][ke*4 + e][r16] = dacc[e];
      __syncthreads();
      if (tid < 256){
        const int bl2 = tid >> 4, fl = tid & 15;
        float v = bd;
#pragma unroll
        for (int ww = 0; ww < 8; ++ww) v += red[ww][bl2][fl];
        const int f = dct*16 + fl, b = db*16 + bl2;
        if (f < F_){
          out[(size_t)b*TF_ + (size_t)t*F_ + f] = v;
          if (t + 1 < T_){
            const bool gt = (((t+1) % 10) < 5);
            const float in = gt ? x[(size_t)b*TF_ + (size_t)(t+1)*F_ + f] : v;
            const u16 hh = f2bf(in);
            st2a(if_hi + b*FX_ + f, hh);
            st2a(if_lo + b*FX_ + f, f2bf(in - bf2f(hh)));
          }
        }
      }
    }
    ++ep; gbar(bar, ep, tid, leader, xcc, n_my, x_act);
  }
}

// ---------- prep: permuted biases, decoder bias, initial in_frame ----------
// permutation: permuted row i = blk*16 + g*4 + u2  <->  original j = (g<<10)|(blk<<2)|u2
__global__ void k_prep(const float* __restrict__ x,
                       const float* bi1, const float* bh1,
                       const float* bi2, const float* bh2,
                       const float* bi3, const float* bh3,
                       const float* bd_in,
                       float* __restrict__ bperm, float* __restrict__ bdec,
                       u16* __restrict__ if_hi, u16* __restrict__ if_lo)
{
  const int i = blockIdx.x * blockDim.x + threadIdx.x;
  if (i < 3*G_){
    const int l = i >> 12, r = i & 4095;
    const int blk = r >> 4, g = (r >> 2) & 3, u2 = r & 3;
    const int j = (g << 10) | (blk << 2) | u2;
    const float* bi = (l == 0) ? bi1 : (l == 1) ? bi2 : bi3;
    const float* bh = (l == 0) ? bh1 : (l == 1) ? bh2 : bh3;
    bperm[i] = bi[j] + bh[j];
  }
  const int i2 = i - 3*G_;
  if (i2 >= 0 && i2 < 192) bdec[i2] = (i2 < F_) ? bd_in[i2] : 0.f;
  const int i3 = i2 - 192;
  if (i3 >= 0 && i3 < B_*FX_){
    const int b = i3 >> 8, f = i3 & 255;
    const float v = (f < F_) ? x[(size_t)b*TF_ + f] : 0.f;   // t=0 is ground-truth
    const u16 hh = f2bf(v);
    if_hi[i3] = hh;
    if_lo[i3] = f2bf(v - bf2f(hh));
  }
}

// ---------- weight convert: fp32 -> bf16, permuted (blk*16 + g*4 + u2) ----------
__global__ void k_wcvt(const float* __restrict__ Wih1, const float* __restrict__ Whh1,
                       const float* __restrict__ Wih2, const float* __restrict__ Whh2,
                       const float* __restrict__ Wih3, const float* __restrict__ Whh3,
                       const float* __restrict__ Wd_in,
                       u16* __restrict__ W1X, u16* __restrict__ W1H,
                       u16* __restrict__ W2,  u16* __restrict__ W3,
                       u16* __restrict__ WD)
{
  const int region = blockIdx.y;
  const size_t stride = (size_t)gridDim.x * blockDim.x;
  const size_t i0 = (size_t)blockIdx.x * blockDim.x + threadIdx.x;
  if (region == 0){
    for (size_t i = i0; i < (size_t)G_*FX_; i += stride){
      const int r = (int)(i >> 8), k = (int)(i & 255);
      const int blk = r >> 4, g = (r >> 2) & 3, u2 = r & 3;
      const int j = (g << 10) | (blk << 2) | u2;
      W1X[i] = f2bf((k < F_) ? Wih1[(size_t)j*F_ + k] : 0.f);
    }
  } else if (region == 1){
    for (size_t i = i0; i < (size_t)G_*H_; i += stride){
      const int r = (int)(i >> 10), k = (int)(i & 1023);
      const int blk = r >> 4, g = (r >> 2) & 3, u2 = r & 3;
      const int j = (g << 10) | (blk << 2) | u2;
      W1H[i] = f2bf(Whh1[(size_t)j*H_ + k]);
    }
  } else if (region == 2){
    for (size_t i = i0; i < (size_t)G_*2048; i += stride){
      const int r = (int)(i >> 11), k = (int)(i & 2047);
      const int blk = r >> 4, g = (r >> 2) & 3, u2 = r & 3;
      const int j = (g << 10) | (blk << 2) | u2;
      W2[i] = f2bf((k < H_) ? Wih2[(size_t)j*H_ + k] : Whh2[(size_t)j*H_ + (k - H_)]);
    }
  } else if (region == 3){
    for (size_t i = i0; i < (size_t)G_*2048; i += stride){
      const int r = (int)(i >> 11), k = (int)(i & 2047);
      const int blk = r >> 4, g = (r >> 2) & 3, u2 = r & 3;
      const int j = (g << 10) | (blk << 2) | u2;
      W3[i] = f2bf((k < H_) ? Wih3[(size_t)j*H_ + k] : Whh3[(size_t)j*H_ + (k - H_)]);
    }
  } else {
    for (size_t i = i0; i < (size_t)176*H_; i += stride){
      const int r = (int)(i >> 10), k = (int)(i & 1023);
      WD[i] = f2bf((r < F_) ? Wd_in[(size_t)r*H_ + k] : 0.f);
    }
  }
}

extern "C" void kernel_launch(void* const* d_in, const int* in_sizes, int n_in,
                              void* d_out, int out_size, void* d_ws, size_t ws_size,
                              hipStream_t stream)
{
  const float* x    = (const float*)d_in[0];
  const float* Wih1 = (const float*)d_in[1];
  const float* bih1 = (const float*)d_in[2];
  const float* Whh1 = (const float*)d_in[3];
  const float* bhh1 = (const float*)d_in[4];
  const float* Wih2 = (const float*)d_in[5];
  const float* bih2 = (const float*)d_in[6];
  const float* Whh2 = (const float*)d_in[7];
  const float* bhh2 = (const float*)d_in[8];
  const float* Wih3 = (const float*)d_in[9];
  const float* bih3 = (const float*)d_in[10];
  const float* Whh3 = (const float*)d_in[11];
  const float* bhh3 = (const float*)d_in[12];
  const float* Wdec = (const float*)d_in[13];
  const float* bdec_in = (const float*)d_in[14];
  float* out = (float*)d_out;

  char* ws = (char*)d_ws;
  size_t off = 0;
  auto alloc = [&](size_t bytes) -> void* {
    void* p = ws + off;
    off = (off + bytes + 255) & ~(size_t)255;
    return p;
  };
  unsigned* bar = (unsigned*)alloc(4096);        // leaf/root/flag/census, 64B-spaced
  u16* h_hi  = (u16*)alloc((size_t)3*2*BH_*2);
  u16* h_lo  = (u16*)alloc((size_t)3*2*BH_*2);
  u16* if_hi = (u16*)alloc((size_t)B_*FX_*2);
  u16* if_lo = (u16*)alloc((size_t)B_*FX_*2);
  const size_t zero_bytes = off;                 // state zone: re-zeroed every launch
  u16* W1X = (u16*)alloc((size_t)G_*FX_*2);
  u16* W1H = (u16*)alloc((size_t)G_*H_*2);
  u16* W2  = (u16*)alloc((size_t)G_*2048*2);
  u16* W3  = (u16*)alloc((size_t)G_*2048*2);
  u16* WD  = (u16*)alloc((size_t)176*H_*2);
  float* bperm = (float*)alloc((size_t)3*G_*4);
  float* bdec  = (float*)alloc((size_t)192*4);

  hipMemsetAsync(d_ws, 0, zero_bytes, stream);
  k_prep<<<180, 256, 0, stream>>>(x, bih1, bhh1, bih2, bhh2, bih3, bhh3, bdec_in,
                                  bperm, bdec, if_hi, if_lo);
  k_wcvt<<<dim3(2048, 5), 256, 0, stream>>>(Wih1, Whh1, Wih2, Whh2, Wih3, Whh3, Wdec,
                                            W1X, W1H, W2, W3, WD);
  k_main<<<NB_, NT_, 0, stream>>>(x, out, W1X, W1H, W2, W3, WD, bperm, bdec,
                                  h_hi, h_lo, if_hi, if_lo, bar);
}

// Round 11
// 20140.839 us; speedup vs baseline: 1.7365x; 1.1002x over previous
//
#include <hip/hip_runtime.h>

typedef unsigned short u16;
typedef __attribute__((ext_vector_type(8))) short bf16x8;
typedef __attribute__((ext_vector_type(4))) float f32x4;

#define MFMA(a,b,c) __builtin_amdgcn_mfma_f32_16x16x32_bf16(a,b,c,0,0,0)

#define B_   128
#define T_   200
#define F_   171
#define FX_  256          // padded frame (8 K-chunks of 32; zero-padded weights)
#define H_   1024
#define G_   4096
#define TF_  (T_*F_)
#define BH_  (B_*H_)
#define NB_  256
#define NT_  512

__device__ __forceinline__ u16 f2bf(float v){
  union { float f; unsigned u; } c; c.f = v;
  unsigned r = (c.u + 0x7fffu + ((c.u >> 16) & 1u)) >> 16;   // RNE
  return (u16)r;
}
__device__ __forceinline__ float bf2f(u16 h){
  union { unsigned u; float f; } c; c.u = ((unsigned)h) << 16; return c.f;
}
__device__ __forceinline__ bf16x8 ld8(const u16* p){
  return *reinterpret_cast<const bf16x8*>(p);
}
// agent-scope write-through stores: visible at MALL, no release fence, no dirty L2 lines
__device__ __forceinline__ void st2a(u16* p, u16 v){
  __hip_atomic_store(p, v, __ATOMIC_RELAXED, __HIP_MEMORY_SCOPE_AGENT);
}
__device__ __forceinline__ void st4a(float* p, float v){
  __hip_atomic_store(p, v, __ATOMIC_RELAXED, __HIP_MEMORY_SCOPE_AGENT);
}
__device__ __forceinline__ float sigm(float v){ return 1.f / (1.f + __expf(-v)); }

// h/if fragment-major layout: tile(bt, kcg) of 16 batch x 32 K stored as 1KB block;
// element (row, khi*8+e) at tile_base + khi*128 + row*8 + e. A wave's A-frag load for
// (bt,kcg) is 64 lanes x 16B = 1KB CONTIGUOUS (8 full 128B lines, sequential).
// h: TPR=32 tiles/batch-row (K=1024); if: TPR=8 (K=256).

// ---------- device barrier (R9-proven): leaf-per-XCD arrive, ONE L2-inv per XCD by leader,
// flag published with agent-scope RELEASE store (lands at MALL), peers poll agent-relaxed ----
__device__ __forceinline__ void gbar(unsigned* bar, unsigned ep, int tid,
                                     bool leader, unsigned xcd,
                                     unsigned n_my, unsigned x_act){
  __syncthreads();                                   // drains vmcnt: st2a/st4a at MALL
  if (tid == 0){
    unsigned* leaf = bar + xcd*16;
    unsigned* root = bar + 256;
    unsigned* flag = bar + 272 + xcd*16;
    const unsigned r = __hip_atomic_fetch_add(leaf, 1u, __ATOMIC_RELAXED, __HIP_MEMORY_SCOPE_AGENT);
    if (r == ep * n_my - 1u)                         // last arriver on this XCD
      __hip_atomic_fetch_add(root, 1u, __ATOMIC_RELAXED, __HIP_MEMORY_SCOPE_AGENT);
    if (leader){
      while (__hip_atomic_load(root, __ATOMIC_RELAXED, __HIP_MEMORY_SCOPE_AGENT) < ep * x_act)
        __builtin_amdgcn_s_sleep(1);
      __builtin_amdgcn_fence(__ATOMIC_ACQUIRE, "agent");   // single buffer_inv for this XCD
      __hip_atomic_store(flag, ep, __ATOMIC_RELEASE, __HIP_MEMORY_SCOPE_AGENT);
    } else {
      while (__hip_atomic_load(flag, __ATOMIC_RELAXED, __HIP_MEMORY_SCOPE_AGENT) < ep)
        __builtin_amdgcn_s_sleep(1);
    }
  }
  asm volatile("" ::: "memory");
  __syncthreads();
}

// ---------- GEMM on resident weights, fragment-major A: KC chunks x 8 batch-tiles ----------
template<int KC, int TPR>
__device__ __forceinline__ void gemm_red_f(
    const bf16x8* wreg, const u16* __restrict__ hb, const u16* __restrict__ lb,
    int kcg0, int lane, int w, int r16, int ke, float (*red)[128][20])
{
  f32x4 acc[8];
#pragma unroll
  for (int bt = 0; bt < 8; ++bt) acc[bt] = (f32x4){0,0,0,0};
#pragma unroll
  for (int kc = 0; kc < KC; ++kc){
#pragma unroll
    for (int bt = 0; bt < 8; ++bt){
      const int off = (bt*TPR + kcg0 + kc)*512 + lane*8;
      acc[bt] = MFMA(ld8(hb + off), wreg[kc], acc[bt]);
      acc[bt] = MFMA(ld8(lb + off), wreg[kc], acc[bt]);
    }
  }
#pragma unroll
  for (int bt = 0; bt < 8; ++bt)
#pragma unroll
    for (int e = 0; e < 4; ++e)
      red[w][bt*16 + ke*4 + e][r16] = acc[bt][e];
}

// ---------- cell update: thread owns (batch bl, unit u2); block owns cols bid*16.. ----------
__device__ __forceinline__ void cell_update(
    const float* bias4, float& c, bool addgp,
    u16* __restrict__ ohh, u16* __restrict__ ohl,
    int bid, int bl, int u2, float (*red)[128][20], float (*gp)[16])
{
  float g[4];
#pragma unroll
  for (int q = 0; q < 4; ++q){
    float s = bias4[q];
#pragma unroll
    for (int ww = 0; ww < 8; ++ww) s += red[ww][bl][q*4 + u2];
    if (addgp) s += gp[bl][q*4 + u2];
    g[q] = s;
  }
  const float cn = sigm(g[1])*c + sigm(g[0])*tanhf(g[2]);
  const float hn = sigm(g[3])*tanhf(cn);
  c = cn;
  const int col = bid*4 + u2;                        // frag-major store position
  const int idx = ((bl >> 4)*32 + (col >> 5))*512 + ((col >> 3) & 3)*128
                + (bl & 15)*8 + (col & 7);
  const u16 hh = f2bf(hn);
  st2a(ohh + idx, hh);
  st2a(ohl + idx, f2bf(hn - bf2f(hh)));
}

// ---------- main persistent kernel: 256 blocks x 512 thr; block = 16 gate-cols, ALL layers ----------
__global__ __attribute__((amdgpu_flat_work_group_size(NT_, NT_)))
           __attribute__((amdgpu_waves_per_eu(2, 2)))
void k_main(
    const float* __restrict__ x, float* __restrict__ out,
    const u16* __restrict__ W1X, const u16* __restrict__ W1H,
    const u16* __restrict__ W2,  const u16* __restrict__ W3,
    const u16* __restrict__ WD,
    const float* __restrict__ bperm, const float* __restrict__ bdec,
    u16* __restrict__ h_hi, u16* __restrict__ h_lo,
    u16* __restrict__ if_hi, u16* __restrict__ if_lo,
    unsigned* __restrict__ bar)
{
  const int tid = threadIdx.x, bid = blockIdx.x;
  const int w = tid >> 6, lane = tid & 63, r16 = lane & 15, ke = lane >> 4;
  const int bl = tid >> 2, u2 = tid & 3;             // cell mapping: 128 b x 4 units
  __shared__ float red[8][128][20];                  // 80 KB K-reduce (padded rows)
  __shared__ float gp[128][16];                      // 8 KB L1 h-part stash
  __shared__ unsigned s_info[3];

  // ---- one-time census: per-XCD rank, block count, active-XCD count (proven R9) ----
  unsigned xcc; asm volatile("s_getreg_b32 %0, hwreg(HW_REG_XCC_ID)" : "=s"(xcc));
  xcc &= 15;
  if (tid == 0){
    unsigned* chk   = bar + 528;
    unsigned* iroot = bar + 560;
    const unsigned rank = __hip_atomic_fetch_add(&chk[xcc], 1u, __ATOMIC_RELAXED, __HIP_MEMORY_SCOPE_AGENT);
    __builtin_amdgcn_fence(__ATOMIC_RELEASE, "agent");
    __hip_atomic_fetch_add(iroot, 1u, __ATOMIC_RELAXED, __HIP_MEMORY_SCOPE_AGENT);
    while (__hip_atomic_load(iroot, __ATOMIC_RELAXED, __HIP_MEMORY_SCOPE_AGENT) < (unsigned)NB_)
      __builtin_amdgcn_s_sleep(1);
    __builtin_amdgcn_fence(__ATOMIC_ACQUIRE, "agent");
    unsigned xact = 0;
    for (int i = 0; i < 16; ++i)
      xact += (__hip_atomic_load(&chk[i], __ATOMIC_RELAXED, __HIP_MEMORY_SCOPE_AGENT) != 0u);
    s_info[0] = rank;
    s_info[1] = __hip_atomic_load(&chk[xcc], __ATOMIC_RELAXED, __HIP_MEMORY_SCOPE_AGENT);
    s_info[2] = xact;
  }
  __syncthreads();
  const bool leader = (s_info[0] == 0u);
  const unsigned n_my = s_info[1], x_act = s_info[2];

  // ---- resident weights: block's 16 gate-cols for all three layers (+WD for dec blocks) ----
  const size_t wrow = (size_t)(bid*16 + r16);
  bf16x8 w2r[8], w3r[8], w1h[4], w1x, wdr[4];
#pragma unroll
  for (int kc = 0; kc < 8; ++kc) w2r[kc] = ld8(W2 + wrow*2048 + w*256 + kc*32 + ke*8);
#pragma unroll
  for (int kc = 0; kc < 8; ++kc) w3r[kc] = ld8(W3 + wrow*2048 + w*256 + kc*32 + ke*8);
#pragma unroll
  for (int kc = 0; kc < 4; ++kc) w1h[kc] = ld8(W1H + wrow*1024 + w*128 + kc*32 + ke*8);
  w1x = ld8(W1X + wrow*FX_ + w*32 + ke*8);

  // decoder block mapping (bid < 88): 11 col-tiles x 8 batch-tiles
  const int dct = bid >> 3, db = bid & 7;
  const float bd = (bid < 88) ? bdec[dct*16 + (tid & 15)] : 0.f;
  if (bid < 88){
#pragma unroll
    for (int kc = 0; kc < 4; ++kc)
      wdr[kc] = ld8(WD + (size_t)(dct*16 + r16)*1024 + w*128 + kc*32 + ke*8);
  } else {
#pragma unroll
    for (int kc = 0; kc < 4; ++kc) wdr[kc] = (bf16x8){0,0,0,0,0,0,0,0};
  }

  float bias[3][4], cs[3] = {0.f, 0.f, 0.f};
#pragma unroll
  for (int l = 0; l < 3; ++l)
#pragma unroll
    for (int q = 0; q < 4; ++q) bias[l][q] = bperm[l*G_ + bid*16 + q*4 + u2];

  // zero the L1 h-part stash (t=0: h0_prev = 0)
  for (int i = tid; i < 128*16; i += NT_) gp[i >> 4][i & 15] = 0.f;
  __syncthreads();

  unsigned ep = 0;
  for (int t = 0; t < T_; ++t){
    const int cur = t & 1, prv = cur ^ 1;
    u16* h0c_h = h_hi + (0*2+cur)*BH_; u16* h0c_l = h_lo + (0*2+cur)*BH_;
    u16* h1c_h = h_hi + (1*2+cur)*BH_; u16* h1c_l = h_lo + (1*2+cur)*BH_;
    u16* h2c_h = h_hi + (2*2+cur)*BH_; u16* h2c_l = h_lo + (2*2+cur)*BH_;
    const u16* h1p_h = h_hi + (1*2+prv)*BH_; const u16* h1p_l = h_lo + (1*2+prv)*BH_;
    const u16* h2p_h = h_hi + (2*2+prv)*BH_; const u16* h2p_l = h_lo + (2*2+prv)*BH_;

    // ---- P1: gates0 = gpart(W1H*h0_prv) + W1X*if(t); cell -> h0_cur ----
    gemm_red_f<1, 8>(&w1x, if_hi, if_lo, w, lane, w, r16, ke, red);
    __syncthreads();
    cell_update(bias[0], cs[0], true, h0c_h, h0c_l, bid, bl, u2, red, gp);
    ++ep; gbar(bar, ep, tid, leader, xcc, n_my, x_act);

    // ---- P2: gates1 = W2 * [h0_cur | h1_prv]; cell -> h1_cur ----
    if (w < 4) gemm_red_f<8, 32>(w2r, h0c_h, h0c_l, w*8,     lane, w, r16, ke, red);
    else       gemm_red_f<8, 32>(w2r, h1p_h, h1p_l, (w-4)*8, lane, w, r16, ke, red);
    __syncthreads();
    cell_update(bias[1], cs[1], false, h1c_h, h1c_l, bid, bl, u2, red, gp);
    ++ep; gbar(bar, ep, tid, leader, xcc, n_my, x_act);

    // ---- P3: gates2 = W3 * [h1_cur | h2_prv]; cell -> h2_cur ----
    if (w < 4) gemm_red_f<8, 32>(w3r, h1c_h, h1c_l, w*8,     lane, w, r16, ke, red);
    else       gemm_red_f<8, 32>(w3r, h2p_h, h2p_l, (w-4)*8, lane, w, r16, ke, red);
    __syncthreads();
    cell_update(bias[2], cs[2], false, h2c_h, h2c_l, bid, bl, u2, red, gp);
    ++ep; gbar(bar, ep, tid, leader, xcc, n_my, x_act);

    // ---- P4: gpart = W1H * h0_cur (all blocks); decoder -> out(t), if(t+1) (88 blocks) ----
    gemm_red_f<4, 32>(w1h, h0c_h, h0c_l, w*4, lane, w, r16, ke, red);
    __syncthreads();
#pragma unroll
    for (int q = 0; q < 4; ++q){
      float s = 0.f;
#pragma unroll
      for (int ww = 0; ww < 8; ++ww) s += red[ww][bl][q*4 + u2];
      gp[bl][q*4 + u2] = s;
    }
    if (bid < 88){
      __syncthreads();                               // red reused by decoder
      f32x4 dacc = {0,0,0,0};
#pragma unroll
      for (int kc = 0; kc < 4; ++kc){
        const int off = (db*32 + w*4 + kc)*512 + lane*8;
        dacc = MFMA(ld8(h2c_h + off), wdr[kc], dacc);
        dacc = MFMA(ld8(h2c_l + off), wdr[kc], dacc);
      }
#pragma unroll
      for (int e = 0; e < 4; ++e) red[w][ke*4 + e][r16] = dacc[e];
      __syncthreads();
      if (tid < 256){
        const int bl2 = tid >> 4, fl = tid & 15;
        float v = bd;
#pragma unroll
        for (int ww = 0; ww < 8; ++ww) v += red[ww][bl2][fl];
        const int f = dct*16 + fl, b = db*16 + bl2;
        if (f < F_){
          st4a(out + (size_t)b*TF_ + (size_t)t*F_ + f, v);
          if (t + 1 < T_){
            const bool gt = (((t+1) % 10) < 5);
            const float in = gt ? x[(size_t)b*TF_ + (size_t)(t+1)*F_ + f] : v;
            const int idx2 = (db*8 + (f >> 5))*512 + ((f >> 3) & 3)*128 + bl2*8 + (f & 7);
            const u16 hh = f2bf(in);
            st2a(if_hi + idx2, hh);
            st2a(if_lo + idx2, f2bf(in - bf2f(hh)));
          }
        }
      }
    }
    ++ep; gbar(bar, ep, tid, leader, xcc, n_my, x_act);
  }
}

// ---------- prep: permuted biases, decoder bias, initial in_frame (frag-major) ----------
// permutation: permuted row i = blk*16 + g*4 + u2  <->  original j = (g<<10)|(blk<<2)|u2
__global__ void k_prep(const float* __restrict__ x,
                       const float* bi1, const float* bh1,
                       const float* bi2, const float* bh2,
                       const float* bi3, const float* bh3,
                       const float* bd_in,
                       float* __restrict__ bperm, float* __restrict__ bdec,
                       u16* __restrict__ if_hi, u16* __restrict__ if_lo)
{
  const int i = blockIdx.x * blockDim.x + threadIdx.x;
  if (i < 3*G_){
    const int l = i >> 12, r = i & 4095;
    const int blk = r >> 4, g = (r >> 2) & 3, u2 = r & 3;
    const int j = (g << 10) | (blk << 2) | u2;
    const float* bi = (l == 0) ? bi1 : (l == 1) ? bi2 : bi3;
    const float* bh = (l == 0) ? bh1 : (l == 1) ? bh2 : bh3;
    bperm[i] = bi[j] + bh[j];
  }
  const int i2 = i - 3*G_;
  if (i2 >= 0 && i2 < 192) bdec[i2] = (i2 < F_) ? bd_in[i2] : 0.f;
  const int i3 = i2 - 192;
  if (i3 >= 0 && i3 < B_*FX_){
    const int b = i3 >> 8, f = i3 & 255;
    const float v = (f < F_) ? x[(size_t)b*TF_ + f] : 0.f;   // t=0 is ground-truth
    const int idx = ((b >> 4)*8 + (f >> 5))*512 + ((f >> 3) & 3)*128 + (b & 15)*8 + (f & 7);
    const u16 hh = f2bf(v);
    if_hi[idx] = hh;
    if_lo[idx] = f2bf(v - bf2f(hh));
  }
}

// ---------- weight convert: fp32 -> bf16, permuted (blk*16 + g*4 + u2) ----------
__global__ void k_wcvt(const float* __restrict__ Wih1, const float* __restrict__ Whh1,
                       const float* __restrict__ Wih2, const float* __restrict__ Whh2,
                       const float* __restrict__ Wih3, const float* __restrict__ Whh3,
                       const float* __restrict__ Wd_in,
                       u16* __restrict__ W1X, u16* __restrict__ W1H,
                       u16* __restrict__ W2,  u16* __restrict__ W3,
                       u16* __restrict__ WD)
{
  const int region = blockIdx.y;
  const size_t stride = (size_t)gridDim.x * blockDim.x;
  const size_t i0 = (size_t)blockIdx.x * blockDim.x + threadIdx.x;
  if (region == 0){
    for (size_t i = i0; i < (size_t)G_*FX_; i += stride){
      const int r = (int)(i >> 8), k = (int)(i & 255);
      const int blk = r >> 4, g = (r >> 2) & 3, u2 = r & 3;
      const int j = (g << 10) | (blk << 2) | u2;
      W1X[i] = f2bf((k < F_) ? Wih1[(size_t)j*F_ + k] : 0.f);
    }
  } else if (region == 1){
    for (size_t i = i0; i < (size_t)G_*H_; i += stride){
      const int r = (int)(i >> 10), k = (int)(i & 1023);
      const int blk = r >> 4, g = (r >> 2) & 3, u2 = r & 3;
      const int j = (g << 10) | (blk << 2) | u2;
      W1H[i] = f2bf(Whh1[(size_t)j*H_ + k]);
    }
  } else if (region == 2){
    for (size_t i = i0; i < (size_t)G_*2048; i += stride){
      const int r = (int)(i >> 11), k = (int)(i & 2047);
      const int blk = r >> 4, g = (r >> 2) & 3, u2 = r & 3;
      const int j = (g << 10) | (blk << 2) | u2;
      W2[i] = f2bf((k < H_) ? Wih2[(size_t)j*H_ + k] : Whh2[(size_t)j*H_ + (k - H_)]);
    }
  } else if (region == 3){
    for (size_t i = i0; i < (size_t)G_*2048; i += stride){
      const int r = (int)(i >> 11), k = (int)(i & 2047);
      const int blk = r >> 4, g = (r >> 2) & 3, u2 = r & 3;
      const int j = (g << 10) | (blk << 2) | u2;
      W3[i] = f2bf((k < H_) ? Wih3[(size_t)j*H_ + k] : Whh3[(size_t)j*H_ + (k - H_)]);
    }
  } else {
    for (size_t i = i0; i < (size_t)176*H_; i += stride){
      const int r = (int)(i >> 10), k = (int)(i & 1023);
      WD[i] = f2bf((r < F_) ? Wd_in[(size_t)r*H_ + k] : 0.f);
    }
  }
}

extern "C" void kernel_launch(void* const* d_in, const int* in_sizes, int n_in,
                              void* d_out, int out_size, void* d_ws, size_t ws_size,
                              hipStream_t stream)
{
  const float* x    = (const float*)d_in[0];
  const float* Wih1 = (const float*)d_in[1];
  const float* bih1 = (const float*)d_in[2];
  const float* Whh1 = (const float*)d_in[3];
  const float* bhh1 = (const float*)d_in[4];
  const float* Wih2 = (const float*)d_in[5];
  const float* bih2 = (const float*)d_in[6];
  const float* Whh2 = (const float*)d_in[7];
  const float* bhh2 = (const float*)d_in[8];
  const float* Wih3 = (const float*)d_in[9];
  const float* bih3 = (const float*)d_in[10];
  const float* Whh3 = (const float*)d_in[11];
  const float* bhh3 = (const float*)d_in[12];
  const float* Wdec = (const float*)d_in[13];
  const float* bdec_in = (const float*)d_in[14];
  float* out = (float*)d_out;

  char* ws = (char*)d_ws;
  size_t off = 0;
  auto alloc = [&](size_t bytes) -> void* {
    void* p = ws + off;
    off = (off + bytes + 255) & ~(size_t)255;
    return p;
  };
  unsigned* bar = (unsigned*)alloc(4096);        // leaf/root/flag/census, 64B-spaced
  u16* h_hi  = (u16*)alloc((size_t)3*2*BH_*2);
  u16* h_lo  = (u16*)alloc((size_t)3*2*BH_*2);
  u16* if_hi = (u16*)alloc((size_t)B_*FX_*2);
  u16* if_lo = (u16*)alloc((size_t)B_*FX_*2);
  const size_t zero_bytes = off;                 // state zone: re-zeroed every launch
  u16* W1X = (u16*)alloc((size_t)G_*FX_*2);
  u16* W1H = (u16*)alloc((size_t)G_*H_*2);
  u16* W2  = (u16*)alloc((size_t)G_*2048*2);
  u16* W3  = (u16*)alloc((size_t)G_*2048*2);
  u16* WD  = (u16*)alloc((size_t)176*H_*2);
  float* bperm = (float*)alloc((size_t)3*G_*4);
  float* bdec  = (float*)alloc((size_t)192*4);

  hipMemsetAsync(d_ws, 0, zero_bytes, stream);
  k_prep<<<180, 256, 0, stream>>>(x, bih1, bhh1, bih2, bhh2, bih3, bhh3, bdec_in,
                                  bperm, bdec, if_hi, if_lo);
  k_wcvt<<<dim3(2048, 5), 256, 0, stream>>>(Wih1, Whh1, Wih2, Whh2, Wih3, Whh3, Wdec,
                                            W1X, W1H, W2, W3, WD);
  k_main<<<NB_, NT_, 0, stream>>>(x, out, W1X, W1H, W2, W3, WD, bperm, bdec,
                                  h_hi, h_lo, if_hi, if_lo, bar);
}

// Round 12
// 10489.538 us; speedup vs baseline: 3.3342x; 1.9201x over previous
//
#include <hip/hip_runtime.h>

typedef unsigned short u16;
typedef __attribute__((ext_vector_type(8))) short bf16x8;
typedef __attribute__((ext_vector_type(4))) float f32x4;

#define MFMA(a,b,c) __builtin_amdgcn_mfma_f32_16x16x32_bf16(a,b,c,0,0,0)

#define B_   128
#define T_   200
#define F_   171
#define FX_  256          // padded frame (8 K-chunks of 32; zero-padded weights)
#define H_   1024
#define G_   4096
#define TF_  (T_*F_)
#define BH_  (B_*H_)
#define NB_  256
#define NT_  512

__device__ __forceinline__ u16 f2bf(float v){
  union { float f; unsigned u; } c; c.f = v;
  unsigned r = (c.u + 0x7fffu + ((c.u >> 16) & 1u)) >> 16;   // RNE
  return (u16)r;
}
__device__ __forceinline__ float bf2f(u16 h){
  union { unsigned u; float f; } c; c.u = ((unsigned)h) << 16; return c.f;
}
__device__ __forceinline__ bf16x8 ld8(const u16* p){
  return *reinterpret_cast<const bf16x8*>(p);
}
// agent-scope write-through stores: visible at MALL, no release fence, no dirty L2 lines
__device__ __forceinline__ void st2a(u16* p, u16 v){
  __hip_atomic_store(p, v, __ATOMIC_RELAXED, __HIP_MEMORY_SCOPE_AGENT);
}
__device__ __forceinline__ void st4a(float* p, float v){
  __hip_atomic_store(p, v, __ATOMIC_RELAXED, __HIP_MEMORY_SCOPE_AGENT);
}
__device__ __forceinline__ float sigm(float v){ return 1.f / (1.f + __expf(-v)); }

// h/if fragment-major layout: tile(bt, kcg) of 16 batch x 32 K stored as 1KB block;
// element (row, khi*8+e) at tile_base + khi*128 + row*8 + e. A wave's A-frag load for
// (bt,kcg) is 64 lanes x 16B = 1KB CONTIGUOUS (8 full 128B lines, sequential).
// h: TPR=32 tiles/batch-row (K=1024); if: TPR=8 (K=256).

// ---------- device barrier (R9/R11-proven): leaf-per-XCD arrive, ONE L2-inv per XCD by
// leader, flag published with agent-scope RELEASE store (MALL), peers poll agent-relaxed ----
__device__ __forceinline__ void gbar(unsigned* bar, unsigned ep, int tid,
                                     bool leader, unsigned xcd,
                                     unsigned n_my, unsigned x_act){
  __syncthreads();                                   // drains vmcnt: st2a/st4a at MALL
  if (tid == 0){
    unsigned* leaf = bar + xcd*16;
    unsigned* root = bar + 256;
    unsigned* flag = bar + 272 + xcd*16;
    const unsigned r = __hip_atomic_fetch_add(leaf, 1u, __ATOMIC_RELAXED, __HIP_MEMORY_SCOPE_AGENT);
    if (r == ep * n_my - 1u)                         // last arriver on this XCD
      __hip_atomic_fetch_add(root, 1u, __ATOMIC_RELAXED, __HIP_MEMORY_SCOPE_AGENT);
    if (leader){
      while (__hip_atomic_load(root, __ATOMIC_RELAXED, __HIP_MEMORY_SCOPE_AGENT) < ep * x_act)
        __builtin_amdgcn_s_sleep(1);
      __builtin_amdgcn_fence(__ATOMIC_ACQUIRE, "agent");   // single buffer_inv for this XCD
      __hip_atomic_store(flag, ep, __ATOMIC_RELEASE, __HIP_MEMORY_SCOPE_AGENT);
    } else {
      while (__hip_atomic_load(flag, __ATOMIC_RELAXED, __HIP_MEMORY_SCOPE_AGENT) < ep)
        __builtin_amdgcn_s_sleep(1);
    }
  }
  asm volatile("" ::: "memory");
  __syncthreads();
}

// ---------- GEMM on resident weights, fragment-major A (single bf16 stream) ----------
template<int KC, int TPR>
__device__ __forceinline__ void gemm_red_f(
    const bf16x8* wreg, const u16* __restrict__ hb,
    int kcg0, int lane, int w, int r16, int ke, float (*red)[128][20])
{
  f32x4 acc[8];
#pragma unroll
  for (int bt = 0; bt < 8; ++bt) acc[bt] = (f32x4){0,0,0,0};
#pragma unroll
  for (int kc = 0; kc < KC; ++kc){
#pragma unroll
    for (int bt = 0; bt < 8; ++bt){
      const int off = (bt*TPR + kcg0 + kc)*512 + lane*8;
      acc[bt] = MFMA(ld8(hb + off), wreg[kc], acc[bt]);
    }
  }
#pragma unroll
  for (int bt = 0; bt < 8; ++bt)
#pragma unroll
    for (int e = 0; e < 4; ++e)
      red[w][bt*16 + ke*4 + e][r16] = acc[bt][e];
}

// ---------- cell update: thread owns (batch bl, unit u2); block owns cols bid*16.. ----------
__device__ __forceinline__ void cell_update(
    const float* bias4, float& c, bool addgp,
    u16* __restrict__ ohh,
    int bid, int bl, int u2, float (*red)[128][20], float (*gp)[16])
{
  float g[4];
#pragma unroll
  for (int q = 0; q < 4; ++q){
    float s = bias4[q];
#pragma unroll
    for (int ww = 0; ww < 8; ++ww) s += red[ww][bl][q*4 + u2];
    if (addgp) s += gp[bl][q*4 + u2];
    g[q] = s;
  }
  const float cn = sigm(g[1])*c + sigm(g[0])*tanhf(g[2]);
  const float hn = sigm(g[3])*tanhf(cn);
  c = cn;
  const int col = bid*4 + u2;                        // frag-major store position
  const int idx = ((bl >> 4)*32 + (col >> 5))*512 + ((col >> 3) & 3)*128
                + (bl & 15)*8 + (col & 7);
  st2a(ohh + idx, f2bf(hn));
}

// ---------- main persistent kernel: 256 blocks x 512 thr; block = 16 gate-cols, ALL layers ----------
__global__ __attribute__((amdgpu_flat_work_group_size(NT_, NT_)))
           __attribute__((amdgpu_waves_per_eu(2, 2)))
void k_main(
    const float* __restrict__ x, float* __restrict__ out,
    const u16* __restrict__ W1X, const u16* __restrict__ W1H,
    const u16* __restrict__ W2,  const u16* __restrict__ W3,
    const u16* __restrict__ WD,
    const float* __restrict__ bperm, const float* __restrict__ bdec,
    u16* __restrict__ h_hi, u16* __restrict__ if_hi,
    unsigned* __restrict__ bar)
{
  const int tid = threadIdx.x, bid = blockIdx.x;
  const int w = tid >> 6, lane = tid & 63, r16 = lane & 15, ke = lane >> 4;
  const int bl = tid >> 2, u2 = tid & 3;             // cell mapping: 128 b x 4 units
  __shared__ float red[8][128][20];                  // 80 KB K-reduce (padded rows)
  __shared__ float gp[128][16];                      // 8 KB L1 h-part stash
  __shared__ unsigned s_info[3];

  // ---- one-time census: per-XCD rank, block count, active-XCD count (proven R9) ----
  unsigned xcc; asm volatile("s_getreg_b32 %0, hwreg(HW_REG_XCC_ID)" : "=s"(xcc));
  xcc &= 15;
  if (tid == 0){
    unsigned* chk   = bar + 528;
    unsigned* iroot = bar + 560;
    const unsigned rank = __hip_atomic_fetch_add(&chk[xcc], 1u, __ATOMIC_RELAXED, __HIP_MEMORY_SCOPE_AGENT);
    __builtin_amdgcn_fence(__ATOMIC_RELEASE, "agent");
    __hip_atomic_fetch_add(iroot, 1u, __ATOMIC_RELAXED, __HIP_MEMORY_SCOPE_AGENT);
    while (__hip_atomic_load(iroot, __ATOMIC_RELAXED, __HIP_MEMORY_SCOPE_AGENT) < (unsigned)NB_)
      __builtin_amdgcn_s_sleep(1);
    __builtin_amdgcn_fence(__ATOMIC_ACQUIRE, "agent");
    unsigned xact = 0;
    for (int i = 0; i < 16; ++i)
      xact += (__hip_atomic_load(&chk[i], __ATOMIC_RELAXED, __HIP_MEMORY_SCOPE_AGENT) != 0u);
    s_info[0] = rank;
    s_info[1] = __hip_atomic_load(&chk[xcc], __ATOMIC_RELAXED, __HIP_MEMORY_SCOPE_AGENT);
    s_info[2] = xact;
  }
  __syncthreads();
  const bool leader = (s_info[0] == 0u);
  const unsigned n_my = s_info[1], x_act = s_info[2];

  // ---- resident weights: block's 16 gate-cols for all three layers (+WD for dec blocks) ----
  const size_t wrow = (size_t)(bid*16 + r16);
  bf16x8 w2r[8], w3r[8], w1h[4], w1x, wdr[4];
#pragma unroll
  for (int kc = 0; kc < 8; ++kc) w2r[kc] = ld8(W2 + wrow*2048 + w*256 + kc*32 + ke*8);
#pragma unroll
  for (int kc = 0; kc < 8; ++kc) w3r[kc] = ld8(W3 + wrow*2048 + w*256 + kc*32 + ke*8);
#pragma unroll
  for (int kc = 0; kc < 4; ++kc) w1h[kc] = ld8(W1H + wrow*1024 + w*128 + kc*32 + ke*8);
  w1x = ld8(W1X + wrow*FX_ + w*32 + ke*8);

  // decoder block mapping (bid < 88): 11 col-tiles x 8 batch-tiles
  const int dct = bid >> 3, db = bid & 7;
  const float bd = (bid < 88) ? bdec[dct*16 + (tid & 15)] : 0.f;
  if (bid < 88){
#pragma unroll
    for (int kc = 0; kc < 4; ++kc)
      wdr[kc] = ld8(WD + (size_t)(dct*16 + r16)*1024 + w*128 + kc*32 + ke*8);
  } else {
#pragma unroll
    for (int kc = 0; kc < 4; ++kc) wdr[kc] = (bf16x8){0,0,0,0,0,0,0,0};
  }

  float bias[3][4], cs[3] = {0.f, 0.f, 0.f};
#pragma unroll
  for (int l = 0; l < 3; ++l)
#pragma unroll
    for (int q = 0; q < 4; ++q) bias[l][q] = bperm[l*G_ + bid*16 + q*4 + u2];

  // zero the L1 h-part stash (t=0: h0_prev = 0)
  for (int i = tid; i < 128*16; i += NT_) gp[i >> 4][i & 15] = 0.f;
  __syncthreads();

  unsigned ep = 0;
  for (int t = 0; t < T_; ++t){
    const int cur = t & 1, prv = cur ^ 1;
    u16* h0c = h_hi + (0*2+cur)*BH_;
    u16* h1c = h_hi + (1*2+cur)*BH_;
    u16* h2c = h_hi + (2*2+cur)*BH_;
    const u16* h1p = h_hi + (1*2+prv)*BH_;
    const u16* h2p = h_hi + (2*2+prv)*BH_;

    // ---- P1: gates0 = gpart(W1H*h0_prv) + W1X*if(t); cell -> h0_cur ----
    gemm_red_f<1, 8>(&w1x, if_hi, w, lane, w, r16, ke, red);
    __syncthreads();
    cell_update(bias[0], cs[0], true, h0c, bid, bl, u2, red, gp);
    ++ep; gbar(bar, ep, tid, leader, xcc, n_my, x_act);

    // ---- P2: gates1 = W2 * [h0_cur | h1_prv]; cell -> h1_cur ----
    if (w < 4) gemm_red_f<8, 32>(w2r, h0c, w*8,     lane, w, r16, ke, red);
    else       gemm_red_f<8, 32>(w2r, h1p, (w-4)*8, lane, w, r16, ke, red);
    __syncthreads();
    cell_update(bias[1], cs[1], false, h1c, bid, bl, u2, red, gp);
    ++ep; gbar(bar, ep, tid, leader, xcc, n_my, x_act);

    // ---- P3: gates2 = W3 * [h1_cur | h2_prv]; cell -> h2_cur ----
    if (w < 4) gemm_red_f<8, 32>(w3r, h1c, w*8,     lane, w, r16, ke, red);
    else       gemm_red_f<8, 32>(w3r, h2p, (w-4)*8, lane, w, r16, ke, red);
    __syncthreads();
    cell_update(bias[2], cs[2], false, h2c, bid, bl, u2, red, gp);
    ++ep; gbar(bar, ep, tid, leader, xcc, n_my, x_act);

    // ---- P4: gpart = W1H * h0_cur (all blocks); decoder -> out(t), if(t+1) (88 blocks) ----
    gemm_red_f<4, 32>(w1h, h0c, w*4, lane, w, r16, ke, red);
    __syncthreads();
#pragma unroll
    for (int q = 0; q < 4; ++q){
      float s = 0.f;
#pragma unroll
      for (int ww = 0; ww < 8; ++ww) s += red[ww][bl][q*4 + u2];
      gp[bl][q*4 + u2] = s;
    }
    if (bid < 88){
      __syncthreads();                               // red reused by decoder
      f32x4 dacc = {0,0,0,0};
#pragma unroll
      for (int kc = 0; kc < 4; ++kc){
        const int off = (db*32 + w*4 + kc)*512 + lane*8;
        dacc = MFMA(ld8(h2c + off), wdr[kc], dacc);
      }
#pragma unroll
      for (int e = 0; e < 4; ++e) red[w][ke*4 + e][r16] = dacc[e];
      __syncthreads();
      if (tid < 256){
        const int bl2 = tid >> 4, fl = tid & 15;
        float v = bd;
#pragma unroll
        for (int ww = 0; ww < 8; ++ww) v += red[ww][bl2][fl];
        const int f = dct*16 + fl, b = db*16 + bl2;
        if (f < F_){
          st4a(out + (size_t)b*TF_ + (size_t)t*F_ + f, v);
          if (t + 1 < T_){
            const bool gt = (((t+1) % 10) < 5);
            const float in = gt ? x[(size_t)b*TF_ + (size_t)(t+1)*F_ + f] : v;
            const int idx2 = (db*8 + (f >> 5))*512 + ((f >> 3) & 3)*128 + bl2*8 + (f & 7);
            st2a(if_hi + idx2, f2bf(in));
          }
        }
      }
    }
    ++ep; gbar(bar, ep, tid, leader, xcc, n_my, x_act);
  }
}

// ---------- prep: permuted biases, decoder bias, initial in_frame (frag-major) ----------
// permutation: permuted row i = blk*16 + g*4 + u2  <->  original j = (g<<10)|(blk<<2)|u2
__global__ void k_prep(const float* __restrict__ x,
                       const float* bi1, const float* bh1,
                       const float* bi2, const float* bh2,
                       const float* bi3, const float* bh3,
                       const float* bd_in,
                       float* __restrict__ bperm, float* __restrict__ bdec,
                       u16* __restrict__ if_hi)
{
  const int i = blockIdx.x * blockDim.x + threadIdx.x;
  if (i < 3*G_){
    const int l = i >> 12, r = i & 4095;
    const int blk = r >> 4, g = (r >> 2) & 3, u2 = r & 3;
    const int j = (g << 10) | (blk << 2) | u2;
    const float* bi = (l == 0) ? bi1 : (l == 1) ? bi2 : bi3;
    const float* bh = (l == 0) ? bh1 : (l == 1) ? bh2 : bh3;
    bperm[i] = bi[j] + bh[j];
  }
  const int i2 = i - 3*G_;
  if (i2 >= 0 && i2 < 192) bdec[i2] = (i2 < F_) ? bd_in[i2] : 0.f;
  const int i3 = i2 - 192;
  if (i3 >= 0 && i3 < B_*FX_){
    const int b = i3 >> 8, f = i3 & 255;
    const float v = (f < F_) ? x[(size_t)b*TF_ + f] : 0.f;   // t=0 is ground-truth
    const int idx = ((b >> 4)*8 + (f >> 5))*512 + ((f >> 3) & 3)*128 + (b & 15)*8 + (f & 7);
    if_hi[idx] = f2bf(v);
  }
}

// ---------- weight convert: fp32 -> bf16, permuted (blk*16 + g*4 + u2) ----------
__global__ void k_wcvt(const float* __restrict__ Wih1, const float* __restrict__ Whh1,
                       const float* __restrict__ Wih2, const float* __restrict__ Whh2,
                       const float* __restrict__ Wih3, const float* __restrict__ Whh3,
                       const float* __restrict__ Wd_in,
                       u16* __restrict__ W1X, u16* __restrict__ W1H,
                       u16* __restrict__ W2,  u16* __restrict__ W3,
                       u16* __restrict__ WD)
{
  const int region = blockIdx.y;
  const size_t stride = (size_t)gridDim.x * blockDim.x;
  const size_t i0 = (size_t)blockIdx.x * blockDim.x + threadIdx.x;
  if (region == 0){
    for (size_t i = i0; i < (size_t)G_*FX_; i += stride){
      const int r = (int)(i >> 8), k = (int)(i & 255);
      const int blk = r >> 4, g = (r >> 2) & 3, u2 = r & 3;
      const int j = (g << 10) | (blk << 2) | u2;
      W1X[i] = f2bf((k < F_) ? Wih1[(size_t)j*F_ + k] : 0.f);
    }
  } else if (region == 1){
    for (size_t i = i0; i < (size_t)G_*H_; i += stride){
      const int r = (int)(i >> 10), k = (int)(i & 1023);
      const int blk = r >> 4, g = (r >> 2) & 3, u2 = r & 3;
      const int j = (g << 10) | (blk << 2) | u2;
      W1H[i] = f2bf(Whh1[(size_t)j*H_ + k]);
    }
  } else if (region == 2){
    for (size_t i = i0; i < (size_t)G_*2048; i += stride){
      const int r = (int)(i >> 11), k = (int)(i & 2047);
      const int blk = r >> 4, g = (r >> 2) & 3, u2 = r & 3;
      const int j = (g << 10) | (blk << 2) | u2;
      W2[i] = f2bf((k < H_) ? Wih2[(size_t)j*H_ + k] : Whh2[(size_t)j*H_ + (k - H_)]);
    }
  } else if (region == 3){
    for (size_t i = i0; i < (size_t)G_*2048; i += stride){
      const int r = (int)(i >> 11), k = (int)(i & 2047);
      const int blk = r >> 4, g = (r >> 2) & 3, u2 = r & 3;
      const int j = (g << 10) | (blk << 2) | u2;
      W3[i] = f2bf((k < H_) ? Wih3[(size_t)j*H_ + k] : Whh3[(size_t)j*H_ + (k - H_)]);
    }
  } else {
    for (size_t i = i0; i < (size_t)176*H_; i += stride){
      const int r = (int)(i >> 10), k = (int)(i & 1023);
      WD[i] = f2bf((r < F_) ? Wd_in[(size_t)r*H_ + k] : 0.f);
    }
  }
}

extern "C" void kernel_launch(void* const* d_in, const int* in_sizes, int n_in,
                              void* d_out, int out_size, void* d_ws, size_t ws_size,
                              hipStream_t stream)
{
  const float* x    = (const float*)d_in[0];
  const float* Wih1 = (const float*)d_in[1];
  const float* bih1 = (const float*)d_in[2];
  const float* Whh1 = (const float*)d_in[3];
  const float* bhh1 = (const float*)d_in[4];
  const float* Wih2 = (const float*)d_in[5];
  const float* bih2 = (const float*)d_in[6];
  const float* Whh2 = (const float*)d_in[7];
  const float* bhh2 = (const float*)d_in[8];
  const float* Wih3 = (const float*)d_in[9];
  const float* bih3 = (const float*)d_in[10];
  const float* Whh3 = (const float*)d_in[11];
  const float* bhh3 = (const float*)d_in[12];
  const float* Wdec = (const float*)d_in[13];
  const float* bdec_in = (const float*)d_in[14];
  float* out = (float*)d_out;

  char* ws = (char*)d_ws;
  size_t off = 0;
  auto alloc = [&](size_t bytes) -> void* {
    void* p = ws + off;
    off = (off + bytes + 255) & ~(size_t)255;
    return p;
  };
  unsigned* bar = (unsigned*)alloc(4096);        // leaf/root/flag/census, 64B-spaced
  u16* h_hi  = (u16*)alloc((size_t)3*2*BH_*2);
  u16* if_hi = (u16*)alloc((size_t)B_*FX_*2);
  const size_t zero_bytes = off;                 // state zone: re-zeroed every launch
  u16* W1X = (u16*)alloc((size_t)G_*FX_*2);
  u16* W1H = (u16*)alloc((size_t)G_*H_*2);
  u16* W2  = (u16*)alloc((size_t)G_*2048*2);
  u16* W3  = (u16*)alloc((size_t)G_*2048*2);
  u16* WD  = (u16*)alloc((size_t)176*H_*2);
  float* bperm = (float*)alloc((size_t)3*G_*4);
  float* bdec  = (float*)alloc((size_t)192*4);

  hipMemsetAsync(d_ws, 0, zero_bytes, stream);
  k_prep<<<180, 256, 0, stream>>>(x, bih1, bhh1, bih2, bhh2, bih3, bhh3, bdec_in,
                                  bperm, bdec, if_hi);
  k_wcvt<<<dim3(2048, 5), 256, 0, stream>>>(Wih1, Whh1, Wih2, Whh2, Wih3, Whh3, Wdec,
                                            W1X, W1H, W2, W3, WD);
  k_main<<<NB_, NT_, 0, stream>>>(x, out, W1X, W1H, W2, W3, WD, bperm, bdec,
                                  h_hi, if_hi, bar);
}